// Round 16
// baseline (506.116 us; speedup 1.0000x reference)
//
#include <hip/hip_runtime.h>
#include <hip/hip_bf16.h>

// Problem constants (from reference setup_inputs)
#define NN 100000
#define HH 128
#define RR 30
#define RR2 15                      // packed 2x16-bit degree words per dst
#define NE 600000
#define TILE 64
#define EPAD (NE + RR * TILE)
#define NCHMAX (EPAD / TILE)        // max relation chunks (9405)
#define NB_PS ((NN + 255) / 256)    // 391 prefix-sum blocks
#define NBLK_BN 784                 // bn stage-1 blocks (128 rows each)
#define RPB_BN 128
#define DBKT 512                    // degree buckets for dst sort
#define BN_EPS 1e-5f

typedef __bf16 v8bf __attribute__((ext_vector_type(8)));
typedef float  v4f  __attribute__((ext_vector_type(4)));
typedef unsigned int v4u __attribute__((ext_vector_type(4)));

static __device__ __forceinline__ unsigned short f2b(float f) {
    unsigned int u = __float_as_uint(f);
    unsigned int r = (u + 0x7FFF + ((u >> 16) & 1)) >> 16;  // RNE
    return (unsigned short)r;
}

// HW packed f32->bf16 (RNE), gfx950
static __device__ __forceinline__ unsigned int pk_bf16(float lo, float hi) {
    unsigned int r;
    asm("v_cvt_pk_bf16_f32 %0, %1, %2" : "=v"(r) : "v"(lo), "v"(hi));
    return r;
}

// ---------------- histogram: packed per-(dst,rel) degree + per-rel count --------
__global__ void k_hist(const int* __restrict__ dst, const int* __restrict__ et,
                       unsigned int* __restrict__ deg16, int* __restrict__ cnt) {
    __shared__ int lh[RR];
    int t = threadIdx.x;
    if (t < RR) lh[t] = 0;
    __syncthreads();
    int i = blockIdx.x * blockDim.x + t;
    if (i < NE) {
        int d = dst[i], r = et[i];
        atomicAdd(&deg16[(size_t)d * RR2 + (r >> 1)], 1u << ((r & 1) * 16));
        atomicAdd(&lh[r], 1);             // LDS
    }
    __syncthreads();
    if (t < RR && lh[t]) atomicAdd(&cnt[t], lh[t]);
}

// ---------------- per-dst degree from deg16 (coalesced) ----------------
__global__ void k_degsum(const unsigned int* __restrict__ deg16,
                         int* __restrict__ cnt_d) {
    int d = blockIdx.x * blockDim.x + threadIdx.x;
    if (d >= NN) return;
    int s = 0;
#pragma unroll
    for (int r2 = 0; r2 < RR2; ++r2) {
        unsigned int v = deg16[(size_t)d * RR2 + r2];
        s += (int)(v & 0xffffu) + (int)(v >> 16);
    }
    cnt_d[d] = s;
}

// ---------------- scan: relation chunk offsets, pad fill, chunk_rel, cursors ------
__global__ void k_scan(const int* __restrict__ cnt, int* __restrict__ cursor,
                       int* __restrict__ totals,
                       int* __restrict__ src_s, int* __restrict__ dst_s,
                       float* __restrict__ norm_s, int* __restrict__ dpos_s,
                       int* __restrict__ chunk_rel, int need_dst) {
    __shared__ int off[RR + 1];
    if (threadIdx.x == 0) {
        int acc = 0;
        for (int r = 0; r < RR; ++r) {
            off[r] = acc;
            acc += (cnt[r] + TILE - 1) / TILE;
        }
        off[RR] = acc;
        totals[0] = acc * TILE;
    }
    __syncthreads();
    for (int r = 0; r < RR; ++r) {
        for (int c = off[r] + (int)threadIdx.x; c < off[r + 1]; c += blockDim.x)
            chunk_rel[c] = r;
        int begin = off[r] * TILE + cnt[r];
        int end   = off[r + 1] * TILE;
        for (int p = begin + (int)threadIdx.x; p < end; p += blockDim.x) {
            src_s[p] = 0; norm_s[p] = 0.f;
            dpos_s[p] = NE;  // pads dump zeros into unread row NE of xe
            if (need_dst) dst_s[p] = 0;
        }
    }
    if (threadIdx.x == 0)
        for (int r = 0; r < RR; ++r) cursor[r] = off[r] * TILE;
}

// ---------------- hierarchical prefix sum over cnt_d (100k bins) ----------------
__global__ void k_psum1(const int* __restrict__ c, int* __restrict__ bsum) {
    __shared__ int sh[256];
    int i = blockIdx.x * 256 + threadIdx.x;
    sh[threadIdx.x] = (i < NN) ? c[i] : 0;
    __syncthreads();
    for (int s = 128; s > 0; s >>= 1) {
        if (threadIdx.x < s) sh[threadIdx.x] += sh[threadIdx.x + s];
        __syncthreads();
    }
    if (threadIdx.x == 0) bsum[blockIdx.x] = sh[0];
}

__global__ void k_psum2(int* __restrict__ bsum) {
    __shared__ int sh[512];
    int t = threadIdx.x;
    sh[t] = (t < NB_PS) ? bsum[t] : 0;
    __syncthreads();
    if (t == 0) {
        int acc = 0;
        for (int b = 0; b < NB_PS; ++b) { int v = sh[b]; sh[b] = acc; acc += v; }
    }
    __syncthreads();
    if (t < NB_PS) bsum[t] = sh[t];
}

__global__ void k_psum3(const int* __restrict__ c, const int* __restrict__ bscan,
                        int* __restrict__ off, int* __restrict__ cur) {
    __shared__ int sh[256];
    int t = threadIdx.x;
    int i = blockIdx.x * 256 + t;
    int v = (i < NN) ? c[i] : 0;
    sh[t] = v;
    __syncthreads();
    for (int s = 1; s < 256; s <<= 1) {   // Hillis-Steele inclusive scan
        int a = (t >= s) ? sh[t - s] : 0;
        __syncthreads();
        sh[t] += a;
        __syncthreads();
    }
    int excl = sh[t] - v + bscan[blockIdx.x];
    if (i < NN) { off[i] = excl; cur[i] = excl; }
    if (i == 0) off[NN] = NE;
}

// ---------------- degree-bucket histogram (LDS-aggregated) ----------------
__global__ void k_dhist(const int* __restrict__ cnt_d, int* __restrict__ dhist) {
    __shared__ int lh[DBKT];
    for (int i = threadIdx.x; i < DBKT; i += 256) lh[i] = 0;
    __syncthreads();
    int d = blockIdx.x * 256 + threadIdx.x;
    if (d < NN) {
        int b = cnt_d[d]; b = b < DBKT - 1 ? b : DBKT - 1;
        atomicAdd(&lh[b], 1);
    }
    __syncthreads();
    for (int i = threadIdx.x; i < DBKT; i += 256)
        if (lh[i]) atomicAdd(&dhist[i], lh[i]);
}

// ---------------- exclusive prefix over DBKT buckets (1 block) ----------------
__global__ void k_dprefix(const int* __restrict__ dhist, int* __restrict__ dcur) {
    __shared__ int sh[DBKT];
    int t = threadIdx.x;            // 512 threads
    int v = dhist[t];
    sh[t] = v;
    __syncthreads();
    for (int s = 1; s < DBKT; s <<= 1) {
        int a = (t >= s) ? sh[t - s] : 0;
        __syncthreads();
        sh[t] += a;
        __syncthreads();
    }
    dcur[t] = sh[t] - v;            // exclusive
}

// ---------------- scatter dsts into degree-sorted perm ----------------
__global__ void k_dscatter(const int* __restrict__ cnt_d, int* __restrict__ dcur,
                           int* __restrict__ perm) {
    __shared__ int lh[DBKT], lbase[DBKT];
    for (int i = threadIdx.x; i < DBKT; i += 256) lh[i] = 0;
    __syncthreads();
    int d = blockIdx.x * 256 + threadIdx.x;
    int b = 0, lrank = 0;
    bool valid = (d < NN);
    if (valid) {
        b = cnt_d[d]; b = b < DBKT - 1 ? b : DBKT - 1;
        lrank = atomicAdd(&lh[b], 1);
    }
    __syncthreads();
    for (int i = threadIdx.x; i < DBKT; i += 256)
        if (lh[i]) lbase[i] = atomicAdd(&dcur[i], lh[i]);
    __syncthreads();
    if (valid) perm[lbase[b] + lrank] = d;
}

// ---------------- scatter into relation-sorted arrays + dst-slot assignment -------
__global__ void k_scatter(const int* __restrict__ src, const int* __restrict__ dst,
                          const int* __restrict__ et,
                          const unsigned int* __restrict__ deg16,
                          int* __restrict__ cursor, int* __restrict__ cursor_dst,
                          int* __restrict__ src_s, int* __restrict__ dst_s,
                          float* __restrict__ norm_s, int* __restrict__ dpos_s,
                          int need_dst) {
    __shared__ int lh[RR];
    __shared__ int lbase[RR];
    int t = threadIdx.x;
    if (t < RR) lh[t] = 0;
    __syncthreads();
    int i = blockIdx.x * blockDim.x + t;
    int r = 0, d = 0, lrank = 0;
    bool valid = (i < NE);
    if (valid) {
        r = et[i]; d = dst[i];
        lrank = atomicAdd(&lh[r], 1);
    }
    __syncthreads();
    if (t < RR && lh[t]) lbase[t] = atomicAdd(&cursor[t], lh[t]);
    __syncthreads();
    if (valid) {
        int pos = lbase[r] + lrank;
        src_s[pos] = src[i];
        if (need_dst) dst_s[pos] = d;
        int dg = (int)((deg16[(size_t)d * RR2 + (r >> 1)] >> ((r & 1) * 16)) & 0xffffu);
        norm_s[pos] = 1.0f / (float)(dg > 1 ? dg : 1);
        dpos_s[pos] = atomicAdd(&cursor_dst[d], 1);  // slot in dst-sorted xe
    }
}

// ---------------- convert+transpose weights to bf16: Wt[m][c][k] = W[m][k][c] ----
__global__ void k_convW(const float* __restrict__ W, unsigned short* __restrict__ Wt,
                        int total) {
    int idx = blockIdx.x * blockDim.x + threadIdx.x;
    if (idx >= total) return;
    int m = idx / (HH * HH);
    int rem = idx % (HH * HH);
    int k = rem / HH, c = rem % HH;
    Wt[m * HH * HH + c * HH + k] = f2b(W[idx]);
}

// ---------------- embedding lookup -> bf16 h (2 elems/thread, cvt_pk) ------------
__global__ void k_embed(const int* __restrict__ x, const float* __restrict__ emb,
                        unsigned int* __restrict__ hb2) {
    int idx = blockIdx.x * blockDim.x + threadIdx.x;   // uint index (2 bf16)
    if (idx >= NN * HH / 2) return;
    int i = idx >> 6;                 // HH/2 = 64 pairs per row
    int j2 = (idx & 63) * 2;
    const float* p = emb + (size_t)x[i] * HH + j2;
    hb2[idx] = pk_bf16(p[0], p[1]);
}

// ---------------- fused root GEMM + edge aggregation, degree-sorted --------------
// Block handles 64 degree-similar dsts via perm[] -> edge-walk divergence ~0.
__global__ __launch_bounds__(256) void k_rootagg(const unsigned short* __restrict__ hb,
                                                 const unsigned short* __restrict__ rootT,
                                                 const float* __restrict__ bias,
                                                 const int* __restrict__ off,
                                                 const int* __restrict__ perm,
                                                 const unsigned short* __restrict__ xe,
                                                 float* __restrict__ tmp) {
    __shared__ __align__(16) unsigned short Ws[64][HH + 8];   // half of root
    int t = threadIdx.x;
    int base = blockIdx.x * TILE;

    int w = t >> 6, lane = t & 63;
    int lr16 = lane & 15, kg = lane >> 4;
    int slot = w * 16 + lr16;
    int pidx = base + slot;
    bool valid = (pidx < NN);
    int drow = valid ? perm[pidx] : 0;

    v8bf xf[4];
    const unsigned short* hrow = hb + (size_t)drow * HH + kg * 8;
#pragma unroll
    for (int kk = 0; kk < 4; ++kk)
        xf[kk] = *reinterpret_cast<const v8bf*>(hrow + kk * 32);

    v4f acc[8];
#pragma unroll
    for (int n = 0; n < 8; ++n) acc[n] = (v4f){0.f, 0.f, 0.f, 0.f};

    // phase A: root rows 0..63 -> n = 0..3
    for (int i = 0; i < 4; ++i) {
        int idx = t + 256 * i;                       // 1024 uint4 chunks
        int row = idx >> 4, g = idx & 15;
        *reinterpret_cast<uint4*>(&Ws[row][g * 8]) =
            *reinterpret_cast<const uint4*>(rootT + row * HH + g * 8);
    }
    __syncthreads();
#pragma unroll
    for (int n = 0; n < 4; ++n)
#pragma unroll
        for (int kk = 0; kk < 4; ++kk) {
            v8bf wf = *reinterpret_cast<const v8bf*>(&Ws[n * 16 + lr16][kk * 32 + kg * 8]);
            acc[n] = __builtin_amdgcn_mfma_f32_16x16x32_bf16(wf, xf[kk], acc[n], 0, 0, 0);
        }
    __syncthreads();
    // phase B: root rows 64..127 -> n = 4..7
    for (int i = 0; i < 4; ++i) {
        int idx = t + 256 * i;
        int row = idx >> 4, g = idx & 15;
        *reinterpret_cast<uint4*>(&Ws[row][g * 8]) =
            *reinterpret_cast<const uint4*>(rootT + (64 + row) * HH + g * 8);
    }
    __syncthreads();
#pragma unroll
    for (int n = 4; n < 8; ++n)
#pragma unroll
        for (int kk = 0; kk < 4; ++kk) {
            v8bf wf = *reinterpret_cast<const v8bf*>(&Ws[(n - 4) * 16 + lr16][kk * 32 + kg * 8]);
            acc[n] = __builtin_amdgcn_mfma_f32_16x16x32_bf16(wf, xf[kk], acc[n], 0, 0, 0);
        }

    // edge-sum walk: contiguous span, 2-row unroll (16 loads in flight)
    int s = valid ? off[drow] : 0;
    int e = valid ? off[drow + 1] : 0;
    int p = s;
    for (; p + 1 < e; p += 2) {
        const unsigned short* xr0 = xe + (size_t)p * HH + kg * 4;
        const unsigned short* xr1 = xr0 + HH;
        uint2 u0[8], u1[8];
#pragma unroll
        for (int n = 0; n < 8; ++n) {
            u0[n] = *reinterpret_cast<const uint2*>(xr0 + n * 16);
            u1[n] = *reinterpret_cast<const uint2*>(xr1 + n * 16);
        }
#pragma unroll
        for (int n = 0; n < 8; ++n) {
            acc[n][0] += __uint_as_float(u0[n].x << 16) + __uint_as_float(u1[n].x << 16);
            acc[n][1] += __uint_as_float(u0[n].x & 0xffff0000u) + __uint_as_float(u1[n].x & 0xffff0000u);
            acc[n][2] += __uint_as_float(u0[n].y << 16) + __uint_as_float(u1[n].y << 16);
            acc[n][3] += __uint_as_float(u0[n].y & 0xffff0000u) + __uint_as_float(u1[n].y & 0xffff0000u);
        }
    }
    if (p < e) {
        const unsigned short* xr = xe + (size_t)p * HH + kg * 4;
#pragma unroll
        for (int n = 0; n < 8; ++n) {
            uint2 u = *reinterpret_cast<const uint2*>(xr + n * 16);
            acc[n][0] += __uint_as_float(u.x << 16);
            acc[n][1] += __uint_as_float(u.x & 0xffff0000u);
            acc[n][2] += __uint_as_float(u.y << 16);
            acc[n][3] += __uint_as_float(u.y & 0xffff0000u);
        }
    }

    if (valid) {
        float* orow = tmp + (size_t)drow * HH + kg * 4;
#pragma unroll
        for (int n = 0; n < 8; ++n) {
            v4f b = *reinterpret_cast<const v4f*>(bias + n * 16 + kg * 4);
            *reinterpret_cast<v4f*>(orow + n * 16) = acc[n] + b;
        }
    }
}

// ---------------- root GEMM (fallback path only) ----------------
__global__ __launch_bounds__(256) void k_rootgemm(const unsigned short* __restrict__ hb,
                                                  const unsigned short* __restrict__ rootT,
                                                  const float* __restrict__ bias,
                                                  float* __restrict__ tmp) {
    __shared__ __align__(16) unsigned short Xs[TILE][HH + 8];
    __shared__ __align__(16) unsigned short Ws[HH][HH + 8];
    int base = blockIdx.x * TILE;
    int t = threadIdx.x;

    {
        int l = t >> 2, lr = t & 3;
        int row = base + l;
        for (int i = 0; i < 4; ++i) {
            int g = lr + 4 * i;
            uint4 v = {0u, 0u, 0u, 0u};
            if (row < NN) v = *reinterpret_cast<const uint4*>(hb + (size_t)row * HH + g * 8);
            *reinterpret_cast<uint4*>(&Xs[l][g * 8]) = v;
        }
    }
    for (int i = 0; i < 8; ++i) {
        int idx = t + 256 * i;
        int row = idx >> 4, g = idx & 15;
        *reinterpret_cast<uint4*>(&Ws[row][g * 8]) =
            *reinterpret_cast<const uint4*>(rootT + row * HH + g * 8);
    }
    __syncthreads();

    int w = t >> 6, lane = t & 63;
    int lr16 = lane & 15, kg = lane >> 4;
    v4f acc[8];
    for (int n = 0; n < 8; ++n) acc[n] = (v4f){0.f, 0.f, 0.f, 0.f};
#pragma unroll
    for (int kk = 0; kk < 4; ++kk) {
        int k0 = kk * 32 + kg * 8;
        v8bf a = *reinterpret_cast<const v8bf*>(&Xs[w * 16 + lr16][k0]);
#pragma unroll
        for (int n = 0; n < 8; ++n) {
            v8bf b = *reinterpret_cast<const v8bf*>(&Ws[n * 16 + lr16][k0]);
            acc[n] = __builtin_amdgcn_mfma_f32_16x16x32_bf16(a, b, acc[n], 0, 0, 0);
        }
    }
#pragma unroll
    for (int n = 0; n < 8; ++n)
        for (int j = 0; j < 4; ++j) {
            int row = base + w * 16 + kg * 4 + j;
            int col = n * 16 + lr16;
            if (row < NN) tmp[(size_t)row * HH + col] = acc[n][j] + bias[col];
        }
}

// ---------------- edge GEMM -> xe rows: swapped MFMA, reg accs, LDS-reuse repack --
__global__ __launch_bounds__(256) void k_edgegemm_x(const unsigned short* __restrict__ hb,
                                                    const unsigned short* __restrict__ Wt,
                                                    const int* __restrict__ src_s,
                                                    const int* __restrict__ chunk_rel,
                                                    const float* __restrict__ norm_s,
                                                    const int* __restrict__ dpos_s,
                                                    const int* __restrict__ totals,
                                                    unsigned short* __restrict__ xe) {
    int ebase = blockIdx.x * TILE;
    if (ebase >= totals[0]) return;
    __shared__ __align__(16) unsigned short S[HH * (HH + 8)];   // Ws, reused as staging
    int t = threadIdx.x;
    int rel = chunk_rel[blockIdx.x];  // single-relation chunk by construction

    const unsigned short* Wr = Wt + (size_t)rel * HH * HH;
    for (int i = 0; i < 8; ++i) {
        int idx = t + 256 * i;
        int row = idx >> 4, g = idx & 15;
        *reinterpret_cast<uint4*>(&S[row * (HH + 8) + g * 8]) =
            *reinterpret_cast<const uint4*>(Wr + row * HH + g * 8);
    }

    int w = t >> 6, lane = t & 63;
    int lr16 = lane & 15, kg = lane >> 4;
    int slot = w * 16 + lr16;
    int srow = src_s[ebase + slot];
    float nrm = norm_s[ebase + slot];

    v8bf xf[4];
    const unsigned short* hrow = hb + (size_t)srow * HH + kg * 8;
#pragma unroll
    for (int kk = 0; kk < 4; ++kk)
        xf[kk] = *reinterpret_cast<const v8bf*>(hrow + kk * 32);

    __syncthreads();   // Ws staged

    v4f acc[8];
#pragma unroll
    for (int n = 0; n < 8; ++n) acc[n] = (v4f){0.f, 0.f, 0.f, 0.f};
#pragma unroll
    for (int n = 0; n < 8; ++n)
#pragma unroll
        for (int kk = 0; kk < 4; ++kk) {
            v8bf wf = *reinterpret_cast<const v8bf*>(
                &S[(n * 16 + lr16) * (HH + 8) + kk * 32 + kg * 8]);
            acc[n] = __builtin_amdgcn_mfma_f32_16x16x32_bf16(wf, xf[kk], acc[n], 0, 0, 0);
        }

    __syncthreads();   // all Ws reads complete; reuse S[0..8192) as [64][128] staging

    int c = slot & 7;
#pragma unroll
    for (int n = 0; n < 8; ++n) {
        unsigned int w0 = pk_bf16(acc[n][0] * nrm, acc[n][1] * nrm);
        unsigned int w1 = pk_bf16(acc[n][2] * nrm, acc[n][3] * nrm);
        unsigned long long p = (unsigned long long)w0 | ((unsigned long long)w1 << 32);
        int a = n * 4 + kg;                                  // 8B granule index
        int sw = (((a >> 1) ^ c) << 1) | (a & 1);            // swizzled granule
        *reinterpret_cast<unsigned long long*>(&S[slot * HH + sw * 4]) = p;
    }
    __syncthreads();
    {
        int l = t >> 2, lr = t & 3;
        size_t drow = (size_t)dpos_s[ebase + l];
        int cs = l & 7;
        unsigned short* orow = xe + drow * HH;
#pragma unroll
        for (int i = 0; i < 4; ++i) {
            int j = lr + 4 * i;                              // 16B block 0..15
            v4u v = *reinterpret_cast<const v4u*>(&S[l * HH + (j ^ cs) * 8]);
            *reinterpret_cast<v4u*>(orow + j * 8) = v;       // cached store -> L3
        }
    }
}

// ---------------- fallback: atomic edge GEMM (if ws too small for xe) ------------
__global__ __launch_bounds__(256) void k_edgegemm_at(const unsigned short* __restrict__ hb,
                                                     const unsigned short* __restrict__ Wt,
                                                     const int* __restrict__ src_s,
                                                     const int* __restrict__ dst_s,
                                                     const int* __restrict__ chunk_rel,
                                                     const float* __restrict__ norm_s,
                                                     const int* __restrict__ totals,
                                                     float* __restrict__ tmp) {
    int ebase = blockIdx.x * TILE;
    if (ebase >= totals[0]) return;
    __shared__ __align__(16) unsigned short Xs[TILE][HH + 8];
    __shared__ __align__(16) unsigned short Ws[HH][HH + 8];
    __shared__ int   src_l[TILE];
    __shared__ int   dst_l[TILE];
    __shared__ float nrm_l[TILE];
    int t = threadIdx.x;
    if (t < TILE) {
        src_l[t] = src_s[ebase + t];
        dst_l[t] = dst_s[ebase + t];
        nrm_l[t] = norm_s[ebase + t];
    }
    int rel = chunk_rel[blockIdx.x];
    __syncthreads();
    {
        int l = t >> 2, lr = t & 3;
        int srow = src_l[l];
        for (int i = 0; i < 4; ++i) {
            int g = lr + 4 * i;
            *reinterpret_cast<uint4*>(&Xs[l][g * 8]) =
                *reinterpret_cast<const uint4*>(hb + (size_t)srow * HH + g * 8);
        }
    }
    const unsigned short* Wr = Wt + (size_t)rel * HH * HH;
    for (int i = 0; i < 8; ++i) {
        int idx = t + 256 * i;
        int row = idx >> 4, g = idx & 15;
        *reinterpret_cast<uint4*>(&Ws[row][g * 8]) =
            *reinterpret_cast<const uint4*>(Wr + row * HH + g * 8);
    }
    __syncthreads();
    int w = t >> 6, lane = t & 63;
    int lr16 = lane & 15, kg = lane >> 4;
    v4f acc[8];
    for (int n = 0; n < 8; ++n) acc[n] = (v4f){0.f, 0.f, 0.f, 0.f};
#pragma unroll
    for (int kk = 0; kk < 4; ++kk) {
        int k0 = kk * 32 + kg * 8;
        v8bf a = *reinterpret_cast<const v8bf*>(&Xs[w * 16 + lr16][k0]);
#pragma unroll
        for (int n = 0; n < 8; ++n) {
            v8bf b = *reinterpret_cast<const v8bf*>(&Ws[n * 16 + lr16][k0]);
            acc[n] = __builtin_amdgcn_mfma_f32_16x16x32_bf16(a, b, acc[n], 0, 0, 0);
        }
    }
#pragma unroll
    for (int n = 0; n < 8; ++n)
        for (int j = 0; j < 4; ++j) {
            int slot = w * 16 + kg * 4 + j;
            int col  = n * 16 + lr16;
            atomicAdd(&tmp[(size_t)dst_l[slot] * HH + col], acc[n][j] * nrm_l[slot]);
        }
}

// ---------------- BN stage 1: per-block column partial sums (no atomics) ---------
__global__ __launch_bounds__(256) void k_bnsum1(const float* __restrict__ tmp,
                                                float* __restrict__ psum,
                                                float* __restrict__ psq) {
    int t = threadIdx.x;
    int rg = t >> 5, lane = t & 31;           // 8 row-groups x 32 lanes (float4 cols)
    int base = blockIdx.x * RPB_BN;
    v4f s = {0.f, 0.f, 0.f, 0.f}, q = {0.f, 0.f, 0.f, 0.f};
#pragma unroll 4
    for (int i = 0; i < RPB_BN / 8; ++i) {
        int row = base + rg + 8 * i;
        if (row < NN) {
            v4f v = *reinterpret_cast<const v4f*>(tmp + (size_t)row * HH + lane * 4);
            s += v; q += v * v;
        }
    }
    __shared__ v4f shs[8][32], shq[8][32];
    shs[rg][lane] = s; shq[rg][lane] = q;
    __syncthreads();
    if (rg == 0) {
        v4f ts = shs[0][lane], tq = shq[0][lane];
#pragma unroll
        for (int k = 1; k < 8; ++k) { ts += shs[k][lane]; tq += shq[k][lane]; }
        int b = blockIdx.x;
#pragma unroll
        for (int j = 0; j < 4; ++j) {
            psum[(size_t)(lane * 4 + j) * NBLK_BN + b] = ts[j];
            psq [(size_t)(lane * 4 + j) * NBLK_BN + b] = tq[j];
        }
    }
}

// ---------------- BN stage 2: reduce partials, emit affine coefficients ----------
__global__ void k_bnsum2(const float* __restrict__ psum, const float* __restrict__ psq,
                         const float* __restrict__ g, const float* __restrict__ be,
                         float* __restrict__ sc_g, float* __restrict__ shf_g) {
    __shared__ float ssum[HH], ssq[HH];
    int t = threadIdx.x;
    int col = t & 127;
    const float* row = ((t < 128) ? psum : psq) + (size_t)col * NBLK_BN;
    v4f a = {0.f, 0.f, 0.f, 0.f};
    for (int i = 0; i < NBLK_BN / 4; ++i)
        a += *reinterpret_cast<const v4f*>(row + i * 4);
    float acc = a[0] + a[1] + a[2] + a[3];
    if (t < 128) ssum[col] = acc; else ssq[col] = acc;
    __syncthreads();
    if (t < 128) {
        float inv_n = 1.0f / (float)NN;
        float mean = ssum[col] * inv_n;
        float var = ssq[col] * inv_n - mean * mean;
        float sc = g[col] * rsqrtf(var + BN_EPS);
        sc_g[col] = sc;
        shf_g[col] = be[col] - mean * sc;
    }
}

// ---------------- BN apply + ReLU (vectorized float4, cvt_pk pack) ---------------
__global__ void k_bnapply(const float* __restrict__ tmp, const float* __restrict__ sc_g,
                          const float* __restrict__ shf_g,
                          unsigned short* __restrict__ hout,
                          float* __restrict__ fout, int write_bf16) {
    int idx = blockIdx.x * blockDim.x + threadIdx.x;   // float4 index
    if (idx >= NN * HH / 4) return;
    int c4 = (idx & 31) * 4;                            // HH/4 = 32 quads per row
    v4f v  = *reinterpret_cast<const v4f*>(tmp + (size_t)idx * 4);
    v4f sc = *reinterpret_cast<const v4f*>(sc_g + c4);
    v4f sh = *reinterpret_cast<const v4f*>(shf_g + c4);
    v4f r;
#pragma unroll
    for (int j = 0; j < 4; ++j) r[j] = fmaxf(v[j] * sc[j] + sh[j], 0.f);
    if (write_bf16) {
        uint2 u;
        u.x = pk_bf16(r[0], r[1]);
        u.y = pk_bf16(r[2], r[3]);
        *reinterpret_cast<uint2*>(hout + (size_t)idx * 4) = u;
    } else {
        *reinterpret_cast<v4f*>(fout + (size_t)idx * 4) = r;
    }
}

// ---------------- workspace layout (xe LAST so fallback fits small ws) -----------
constexpr size_t OFF_DEG  = 0;                                    // N*RR2*4 = 6 MB
constexpr size_t OFF_HB   = OFF_DEG + (size_t)NN * RR2 * 4;
constexpr size_t OFF_TMP  = OFF_HB + (size_t)NN * HH * 2;
constexpr size_t OFF_W1T  = OFF_TMP + (size_t)NN * HH * 4;
constexpr size_t OFF_W2T  = OFF_W1T + (size_t)RR * HH * HH * 2;
constexpr size_t OFF_R1T  = OFF_W2T + (size_t)RR * HH * HH * 2;
constexpr size_t OFF_R2T  = OFF_R1T + (size_t)HH * HH * 2;
constexpr size_t OFF_SRCS = OFF_R2T + (size_t)HH * HH * 2;
constexpr size_t OFF_DSTS = OFF_SRCS + (size_t)EPAD * 4;
constexpr size_t OFF_NRMS = OFF_DSTS + (size_t)EPAD * 4;
constexpr size_t OFF_DPOS = OFF_NRMS + (size_t)EPAD * 4;
constexpr size_t OFF_CREL = OFF_DPOS + (size_t)EPAD * 4;          // chunk -> relation
constexpr size_t OFF_CNTD = OFF_CREL + ((size_t)NCHMAX * 4 + 255 & ~(size_t)255);
constexpr size_t OFF_OFFD = OFF_CNTD + ((size_t)(NN + 1) * 4 + 255 & ~(size_t)255);
constexpr size_t OFF_CURD = OFF_OFFD + ((size_t)(NN + 1) * 4 + 255 & ~(size_t)255);
constexpr size_t OFF_PERM = OFF_CURD + ((size_t)NN * 4 + 255 & ~(size_t)255);
constexpr size_t OFF_DH   = OFF_PERM + ((size_t)NN * 4 + 255 & ~(size_t)255);
constexpr size_t OFF_DC   = OFF_DH + DBKT * 4;
constexpr size_t OFF_BSUM = OFF_DC + DBKT * 4;
constexpr size_t OFF_CTRL = OFF_BSUM + ((size_t)NB_PS * 4 + 255 & ~(size_t)255);
constexpr size_t OFF_SC   = OFF_CTRL + 512;                       // 128 floats
constexpr size_t OFF_SHF  = OFF_SC + 512;
constexpr size_t OFF_PSUM = OFF_SHF + 512;                        // 128*NBLK_BN floats
constexpr size_t OFF_PSQ  = OFF_PSUM + (size_t)HH * NBLK_BN * 4;
constexpr size_t OFF_XE   = (OFF_PSQ + (size_t)HH * NBLK_BN * 4 + 255) & ~(size_t)255;
constexpr size_t WS_MIN   = OFF_XE;                               // ~101 MB (fallback)
constexpr size_t WS_FULL  = OFF_XE + (size_t)EPAD * HH * 2;       // ~255 MB

extern "C" void kernel_launch(void* const* d_in, const int* in_sizes, int n_in,
                              void* d_out, int out_size, void* d_ws, size_t ws_size,
                              hipStream_t stream) {
    const int*   x     = (const int*)d_in[0];
    const int*   eidx  = (const int*)d_in[1];   // (2,E) row-major: src then dst
    const int*   et    = (const int*)d_in[2];
    const float* emb   = (const float*)d_in[3];
    const float* W1    = (const float*)d_in[4];
    const float* root1 = (const float*)d_in[5];
    const float* b1    = (const float*)d_in[6];
    const float* g1    = (const float*)d_in[7];
    const float* be1   = (const float*)d_in[8];
    const float* W2    = (const float*)d_in[9];
    const float* root2 = (const float*)d_in[10];
    const float* b2    = (const float*)d_in[11];
    const float* g2    = (const float*)d_in[12];
    const float* be2   = (const float*)d_in[13];
    float* out = (float*)d_out;

    if (ws_size < WS_MIN) return;  // diagnosable: out stays poisoned
    const bool full = (ws_size >= WS_FULL);
    const int need_dst = full ? 0 : 1;

    char* ws = (char*)d_ws;
    unsigned int* deg16 = (unsigned int*)(ws + OFF_DEG);
    unsigned short* hb = (unsigned short*)(ws + OFF_HB);
    float* tmp    = (float*)(ws + OFF_TMP);
    unsigned short* W1t = (unsigned short*)(ws + OFF_W1T);
    unsigned short* W2t = (unsigned short*)(ws + OFF_W2T);
    unsigned short* r1t = (unsigned short*)(ws + OFF_R1T);
    unsigned short* r2t = (unsigned short*)(ws + OFF_R2T);
    int*   src_s  = (int*)(ws + OFF_SRCS);
    int*   dst_s  = (int*)(ws + OFF_DSTS);
    float* norm_s = (float*)(ws + OFF_NRMS);
    int*   dpos_s = (int*)(ws + OFF_DPOS);
    int*   crel   = (int*)(ws + OFF_CREL);
    int*   cnt_d  = (int*)(ws + OFF_CNTD);
    int*   off_d  = (int*)(ws + OFF_OFFD);
    int*   cur_d  = (int*)(ws + OFF_CURD);
    int*   perm   = (int*)(ws + OFF_PERM);
    int*   dhist  = (int*)(ws + OFF_DH);
    int*   dcur   = (int*)(ws + OFF_DC);
    int*   bsum   = (int*)(ws + OFF_BSUM);
    int*   cnt    = (int*)(ws + OFF_CTRL);
    int*   cursor = cnt + 32;
    int*   totals = cnt + 64;
    float* sc_g   = (float*)(ws + OFF_SC);
    float* shf_g  = (float*)(ws + OFF_SHF);
    float* psum   = (float*)(ws + OFF_PSUM);
    float* psq    = (float*)(ws + OFF_PSQ);
    unsigned short* xe = (unsigned short*)(ws + OFF_XE);

    const int* srcp = eidx;
    const int* dstp = eidx + NE;

    hipMemsetAsync(deg16, 0, (size_t)NN * RR2 * 4, stream);
    hipMemsetAsync(cnt, 0, 512, stream);
    hipMemsetAsync(dhist, 0, DBKT * 4, stream);

    k_hist<<<(NE + 255) / 256, 256, 0, stream>>>(dstp, et, deg16, cnt);
    k_degsum<<<(NN + 255) / 256, 256, 0, stream>>>(deg16, cnt_d);
    k_scan<<<1, 256, 0, stream>>>(cnt, cursor, totals, src_s, dst_s, norm_s,
                                  dpos_s, crel, need_dst);
    k_psum1<<<NB_PS, 256, 0, stream>>>(cnt_d, bsum);
    k_psum2<<<1, 512, 0, stream>>>(bsum);
    k_psum3<<<NB_PS, 256, 0, stream>>>(cnt_d, bsum, off_d, cur_d);
    k_dhist<<<(NN + 255) / 256, 256, 0, stream>>>(cnt_d, dhist);
    k_dprefix<<<1, DBKT, 0, stream>>>(dhist, dcur);
    k_dscatter<<<(NN + 255) / 256, 256, 0, stream>>>(cnt_d, dcur, perm);
    k_scatter<<<(NE + 255) / 256, 256, 0, stream>>>(srcp, dstp, et, deg16, cursor, cur_d,
                                                    src_s, dst_s, norm_s, dpos_s,
                                                    need_dst);
    k_convW<<<(RR * HH * HH + 255) / 256, 256, 0, stream>>>(W1, W1t, RR * HH * HH);
    k_convW<<<(RR * HH * HH + 255) / 256, 256, 0, stream>>>(W2, W2t, RR * HH * HH);
    k_convW<<<(HH * HH + 255) / 256, 256, 0, stream>>>(root1, r1t, HH * HH);
    k_convW<<<(HH * HH + 255) / 256, 256, 0, stream>>>(root2, r2t, HH * HH);
    k_embed<<<(NN * HH / 2 + 255) / 256, 256, 0, stream>>>(x, emb, (unsigned int*)hb);

    const unsigned short* Wts[2] = {W1t, W2t};
    const unsigned short* rts[2] = {r1t, r2t};
    const float* biases[2] = {b1, b2};
    const float* gs[2]     = {g1, g2};
    const float* bes[2]    = {be1, be2};

    for (int layer = 0; layer < 2; ++layer) {
        if (full) {
            k_edgegemm_x<<<EPAD / TILE, 256, 0, stream>>>(hb, Wts[layer], src_s, crel,
                                                          norm_s, dpos_s, totals, xe);
            k_rootagg<<<(NN + TILE - 1) / TILE, 256, 0, stream>>>(hb, rts[layer],
                                                                  biases[layer], off_d,
                                                                  perm, xe, tmp);
        } else {
            k_rootgemm<<<(NN + TILE - 1) / TILE, 256, 0, stream>>>(hb, rts[layer],
                                                                   biases[layer], tmp);
            k_edgegemm_at<<<EPAD / TILE, 256, 0, stream>>>(hb, Wts[layer], src_s, dst_s,
                                                           crel, norm_s, totals, tmp);
        }
        k_bnsum1<<<NBLK_BN, 256, 0, stream>>>(tmp, psum, psq);
        k_bnsum2<<<1, 256, 0, stream>>>(psum, psq, gs[layer], bes[layer], sc_g, shf_g);
        k_bnapply<<<(NN * HH / 4 + 255) / 256, 256, 0, stream>>>(tmp, sc_g, shf_g,
                                                                 hb, out, layer == 0);
    }
}

// Round 17
// 505.981 us; speedup vs baseline: 1.0003x; 1.0003x over previous
//
#include <hip/hip_runtime.h>
#include <hip/hip_bf16.h>

// Problem constants (from reference setup_inputs)
#define NN 100000
#define HH 128
#define RR 30
#define RR2 15                      // packed 2x16-bit degree words per dst
#define NE 600000
#define TILE 64
#define EPAD (NE + RR * TILE)
#define NCHMAX (EPAD / TILE)        // max relation chunks (9405)
#define NB_PS ((NN + 255) / 256)    // 391 prefix-sum blocks
#define NBLK_BN 784                 // bn stage-1 blocks (128 rows each)
#define RPB_BN 128
#define DBKT 512                    // degree buckets for dst sort
#define BN_EPS 1e-5f

typedef __bf16 v8bf __attribute__((ext_vector_type(8)));
typedef float  v4f  __attribute__((ext_vector_type(4)));
typedef unsigned int v4u __attribute__((ext_vector_type(4)));

static __device__ __forceinline__ unsigned short f2b(float f) {
    unsigned int u = __float_as_uint(f);
    unsigned int r = (u + 0x7FFF + ((u >> 16) & 1)) >> 16;  // RNE
    return (unsigned short)r;
}

// HW packed f32->bf16 (RNE), gfx950
static __device__ __forceinline__ unsigned int pk_bf16(float lo, float hi) {
    unsigned int r;
    asm("v_cvt_pk_bf16_f32 %0, %1, %2" : "=v"(r) : "v"(lo), "v"(hi));
    return r;
}

// ---------------- histogram: packed per-(dst,rel) degree + per-rel count --------
__global__ void k_hist(const int* __restrict__ dst, const int* __restrict__ et,
                       unsigned int* __restrict__ deg16, int* __restrict__ cnt) {
    __shared__ int lh[RR];
    int t = threadIdx.x;
    if (t < RR) lh[t] = 0;
    __syncthreads();
    int i = blockIdx.x * blockDim.x + t;
    if (i < NE) {
        int d = dst[i], r = et[i];
        atomicAdd(&deg16[(size_t)d * RR2 + (r >> 1)], 1u << ((r & 1) * 16));
        atomicAdd(&lh[r], 1);             // LDS
    }
    __syncthreads();
    if (t < RR && lh[t]) atomicAdd(&cnt[t], lh[t]);
}

// ---------------- per-dst degree from deg16 (coalesced) ----------------
__global__ void k_degsum(const unsigned int* __restrict__ deg16,
                         int* __restrict__ cnt_d) {
    int d = blockIdx.x * blockDim.x + threadIdx.x;
    if (d >= NN) return;
    int s = 0;
#pragma unroll
    for (int r2 = 0; r2 < RR2; ++r2) {
        unsigned int v = deg16[(size_t)d * RR2 + r2];
        s += (int)(v & 0xffffu) + (int)(v >> 16);
    }
    cnt_d[d] = s;
}

// ---------------- scan: relation chunk offsets, pad fill, chunk_rel, cursors ------
__global__ void k_scan(const int* __restrict__ cnt, int* __restrict__ cursor,
                       int* __restrict__ totals,
                       int* __restrict__ src_s, int* __restrict__ dst_s,
                       float* __restrict__ norm_s, int* __restrict__ dpos_s,
                       int* __restrict__ chunk_rel, int need_dst) {
    __shared__ int off[RR + 1];
    if (threadIdx.x == 0) {
        int acc = 0;
        for (int r = 0; r < RR; ++r) {
            off[r] = acc;
            acc += (cnt[r] + TILE - 1) / TILE;
        }
        off[RR] = acc;
        totals[0] = acc * TILE;
    }
    __syncthreads();
    for (int r = 0; r < RR; ++r) {
        for (int c = off[r] + (int)threadIdx.x; c < off[r + 1]; c += blockDim.x)
            chunk_rel[c] = r;
        int begin = off[r] * TILE + cnt[r];
        int end   = off[r + 1] * TILE;
        for (int p = begin + (int)threadIdx.x; p < end; p += blockDim.x) {
            src_s[p] = 0; norm_s[p] = 0.f;
            dpos_s[p] = NE;  // pads dump zeros into unread row NE of xe
            if (need_dst) dst_s[p] = 0;
        }
    }
    if (threadIdx.x == 0)
        for (int r = 0; r < RR; ++r) cursor[r] = off[r] * TILE;
}

// ---------------- hierarchical prefix sum over NN counts ----------------
__global__ void k_psum1(const int* __restrict__ c, int* __restrict__ bsum) {
    __shared__ int sh[256];
    int i = blockIdx.x * 256 + threadIdx.x;
    sh[threadIdx.x] = (i < NN) ? c[i] : 0;
    __syncthreads();
    for (int s = 128; s > 0; s >>= 1) {
        if (threadIdx.x < s) sh[threadIdx.x] += sh[threadIdx.x + s];
        __syncthreads();
    }
    if (threadIdx.x == 0) bsum[blockIdx.x] = sh[0];
}

__global__ void k_psum2(int* __restrict__ bsum) {
    __shared__ int sh[512];
    int t = threadIdx.x;
    sh[t] = (t < NB_PS) ? bsum[t] : 0;
    __syncthreads();
    if (t == 0) {
        int acc = 0;
        for (int b = 0; b < NB_PS; ++b) { int v = sh[b]; sh[b] = acc; acc += v; }
    }
    __syncthreads();
    if (t < NB_PS) bsum[t] = sh[t];
}

__global__ void k_psum3(const int* __restrict__ c, const int* __restrict__ bscan,
                        int* __restrict__ off, int* __restrict__ cur) {
    __shared__ int sh[256];
    int t = threadIdx.x;
    int i = blockIdx.x * 256 + t;
    int v = (i < NN) ? c[i] : 0;
    sh[t] = v;
    __syncthreads();
    for (int s = 1; s < 256; s <<= 1) {   // Hillis-Steele inclusive scan
        int a = (t >= s) ? sh[t - s] : 0;
        __syncthreads();
        sh[t] += a;
        __syncthreads();
    }
    int excl = sh[t] - v + bscan[blockIdx.x];
    if (i < NN) { off[i] = excl; cur[i] = excl; }
    if (i == 0) off[NN] = NE;
}

// ---------------- degree-bucket histogram (LDS-aggregated) ----------------
__global__ void k_dhist(const int* __restrict__ cnt_d, int* __restrict__ dhist) {
    __shared__ int lh[DBKT];
    for (int i = threadIdx.x; i < DBKT; i += 256) lh[i] = 0;
    __syncthreads();
    int d = blockIdx.x * 256 + threadIdx.x;
    if (d < NN) {
        int b = cnt_d[d]; b = b < DBKT - 1 ? b : DBKT - 1;
        atomicAdd(&lh[b], 1);
    }
    __syncthreads();
    for (int i = threadIdx.x; i < DBKT; i += 256)
        if (lh[i]) atomicAdd(&dhist[i], lh[i]);
}

// ---------------- exclusive prefix over DBKT buckets (1 block) ----------------
__global__ void k_dprefix(const int* __restrict__ dhist, int* __restrict__ dcur) {
    __shared__ int sh[DBKT];
    int t = threadIdx.x;            // 512 threads
    int v = dhist[t];
    sh[t] = v;
    __syncthreads();
    for (int s = 1; s < DBKT; s <<= 1) {
        int a = (t >= s) ? sh[t - s] : 0;
        __syncthreads();
        sh[t] += a;
        __syncthreads();
    }
    dcur[t] = sh[t] - v;            // exclusive
}

// ---------------- scatter dsts into degree-sorted perm ----------------
__global__ void k_dscatter(const int* __restrict__ cnt_d, int* __restrict__ dcur,
                           int* __restrict__ perm) {
    __shared__ int lh[DBKT], lbase[DBKT];
    for (int i = threadIdx.x; i < DBKT; i += 256) lh[i] = 0;
    __syncthreads();
    int d = blockIdx.x * 256 + threadIdx.x;
    int b = 0, lrank = 0;
    bool valid = (d < NN);
    if (valid) {
        b = cnt_d[d]; b = b < DBKT - 1 ? b : DBKT - 1;
        lrank = atomicAdd(&lh[b], 1);
    }
    __syncthreads();
    for (int i = threadIdx.x; i < DBKT; i += 256)
        if (lh[i]) lbase[i] = atomicAdd(&dcur[i], lh[i]);
    __syncthreads();
    if (valid) perm[lbase[b] + lrank] = d;
}

// ---------------- gather permuted counts: cnt_p[i] = cnt_d[perm[i]] --------------
__global__ void k_permcnt(const int* __restrict__ cnt_d, const int* __restrict__ perm,
                          int* __restrict__ cnt_p) {
    int i = blockIdx.x * blockDim.x + threadIdx.x;
    if (i < NN) cnt_p[i] = cnt_d[perm[i]];
}

// ---------------- scatter perm-ordered offsets to dst-indexed cursors ------------
__global__ void k_permcur(const int* __restrict__ off2, const int* __restrict__ perm,
                          int* __restrict__ cur_d) {
    int i = blockIdx.x * blockDim.x + threadIdx.x;
    if (i < NN) cur_d[perm[i]] = off2[i];
}

// ---------------- scatter into relation-sorted arrays + dst-slot assignment -------
__global__ void k_scatter(const int* __restrict__ src, const int* __restrict__ dst,
                          const int* __restrict__ et,
                          const unsigned int* __restrict__ deg16,
                          int* __restrict__ cursor, int* __restrict__ cursor_dst,
                          int* __restrict__ src_s, int* __restrict__ dst_s,
                          float* __restrict__ norm_s, int* __restrict__ dpos_s,
                          int need_dst) {
    __shared__ int lh[RR];
    __shared__ int lbase[RR];
    int t = threadIdx.x;
    if (t < RR) lh[t] = 0;
    __syncthreads();
    int i = blockIdx.x * blockDim.x + t;
    int r = 0, d = 0, lrank = 0;
    bool valid = (i < NE);
    if (valid) {
        r = et[i]; d = dst[i];
        lrank = atomicAdd(&lh[r], 1);
    }
    __syncthreads();
    if (t < RR && lh[t]) lbase[t] = atomicAdd(&cursor[t], lh[t]);
    __syncthreads();
    if (valid) {
        int pos = lbase[r] + lrank;
        src_s[pos] = src[i];
        if (need_dst) dst_s[pos] = d;
        int dg = (int)((deg16[(size_t)d * RR2 + (r >> 1)] >> ((r & 1) * 16)) & 0xffffu);
        norm_s[pos] = 1.0f / (float)(dg > 1 ? dg : 1);
        dpos_s[pos] = atomicAdd(&cursor_dst[d], 1);  // slot in perm-ordered xe
    }
}

// ---------------- convert+transpose weights to bf16: Wt[m][c][k] = W[m][k][c] ----
__global__ void k_convW(const float* __restrict__ W, unsigned short* __restrict__ Wt,
                        int total) {
    int idx = blockIdx.x * blockDim.x + threadIdx.x;
    if (idx >= total) return;
    int m = idx / (HH * HH);
    int rem = idx % (HH * HH);
    int k = rem / HH, c = rem % HH;
    Wt[m * HH * HH + c * HH + k] = f2b(W[idx]);
}

// ---------------- embedding lookup -> bf16 h (2 elems/thread, cvt_pk) ------------
__global__ void k_embed(const int* __restrict__ x, const float* __restrict__ emb,
                        unsigned int* __restrict__ hb2) {
    int idx = blockIdx.x * blockDim.x + threadIdx.x;   // uint index (2 bf16)
    if (idx >= NN * HH / 2) return;
    int i = idx >> 6;                 // HH/2 = 64 pairs per row
    int j2 = (idx & 63) * 2;
    const float* p = emb + (size_t)x[i] * HH + j2;
    hb2[idx] = pk_bf16(p[0], p[1]);
}

// ---------------- fused root GEMM + edge aggregation, perm-ordered xe ------------
// Block handles 64 degree-similar dsts (perm); xe spans are CONTIGUOUS in perm
// order (off2 indexed by perm position) -> uniform trip counts + sequential reads.
__global__ __launch_bounds__(256) void k_rootagg(const unsigned short* __restrict__ hb,
                                                 const unsigned short* __restrict__ rootT,
                                                 const float* __restrict__ bias,
                                                 const int* __restrict__ off2,
                                                 const int* __restrict__ perm,
                                                 const unsigned short* __restrict__ xe,
                                                 float* __restrict__ tmp) {
    __shared__ __align__(16) unsigned short Ws[64][HH + 8];   // half of root
    int t = threadIdx.x;
    int base = blockIdx.x * TILE;

    int w = t >> 6, lane = t & 63;
    int lr16 = lane & 15, kg = lane >> 4;
    int slot = w * 16 + lr16;
    int pidx = base + slot;
    bool valid = (pidx < NN);
    int drow = valid ? perm[pidx] : 0;

    v8bf xf[4];
    const unsigned short* hrow = hb + (size_t)drow * HH + kg * 8;
#pragma unroll
    for (int kk = 0; kk < 4; ++kk)
        xf[kk] = *reinterpret_cast<const v8bf*>(hrow + kk * 32);

    v4f acc[8];
#pragma unroll
    for (int n = 0; n < 8; ++n) acc[n] = (v4f){0.f, 0.f, 0.f, 0.f};

    // phase A: root rows 0..63 -> n = 0..3
    for (int i = 0; i < 4; ++i) {
        int idx = t + 256 * i;                       // 1024 uint4 chunks
        int row = idx >> 4, g = idx & 15;
        *reinterpret_cast<uint4*>(&Ws[row][g * 8]) =
            *reinterpret_cast<const uint4*>(rootT + row * HH + g * 8);
    }
    __syncthreads();
#pragma unroll
    for (int n = 0; n < 4; ++n)
#pragma unroll
        for (int kk = 0; kk < 4; ++kk) {
            v8bf wf = *reinterpret_cast<const v8bf*>(&Ws[n * 16 + lr16][kk * 32 + kg * 8]);
            acc[n] = __builtin_amdgcn_mfma_f32_16x16x32_bf16(wf, xf[kk], acc[n], 0, 0, 0);
        }
    __syncthreads();
    // phase B: root rows 64..127 -> n = 4..7
    for (int i = 0; i < 4; ++i) {
        int idx = t + 256 * i;
        int row = idx >> 4, g = idx & 15;
        *reinterpret_cast<uint4*>(&Ws[row][g * 8]) =
            *reinterpret_cast<const uint4*>(rootT + (64 + row) * HH + g * 8);
    }
    __syncthreads();
#pragma unroll
    for (int n = 4; n < 8; ++n)
#pragma unroll
        for (int kk = 0; kk < 4; ++kk) {
            v8bf wf = *reinterpret_cast<const v8bf*>(&Ws[(n - 4) * 16 + lr16][kk * 32 + kg * 8]);
            acc[n] = __builtin_amdgcn_mfma_f32_16x16x32_bf16(wf, xf[kk], acc[n], 0, 0, 0);
        }

    // edge-sum walk: contiguous perm-ordered span, 2-row unroll
    int s = valid ? off2[pidx] : 0;
    int e = valid ? off2[pidx + 1] : 0;
    int p = s;
    for (; p + 1 < e; p += 2) {
        const unsigned short* xr0 = xe + (size_t)p * HH + kg * 4;
        const unsigned short* xr1 = xr0 + HH;
        uint2 u0[8], u1[8];
#pragma unroll
        for (int n = 0; n < 8; ++n) {
            u0[n] = *reinterpret_cast<const uint2*>(xr0 + n * 16);
            u1[n] = *reinterpret_cast<const uint2*>(xr1 + n * 16);
        }
#pragma unroll
        for (int n = 0; n < 8; ++n) {
            acc[n][0] += __uint_as_float(u0[n].x << 16) + __uint_as_float(u1[n].x << 16);
            acc[n][1] += __uint_as_float(u0[n].x & 0xffff0000u) + __uint_as_float(u1[n].x & 0xffff0000u);
            acc[n][2] += __uint_as_float(u0[n].y << 16) + __uint_as_float(u1[n].y << 16);
            acc[n][3] += __uint_as_float(u0[n].y & 0xffff0000u) + __uint_as_float(u1[n].y & 0xffff0000u);
        }
    }
    if (p < e) {
        const unsigned short* xr = xe + (size_t)p * HH + kg * 4;
#pragma unroll
        for (int n = 0; n < 8; ++n) {
            uint2 u = *reinterpret_cast<const uint2*>(xr + n * 16);
            acc[n][0] += __uint_as_float(u.x << 16);
            acc[n][1] += __uint_as_float(u.x & 0xffff0000u);
            acc[n][2] += __uint_as_float(u.y << 16);
            acc[n][3] += __uint_as_float(u.y & 0xffff0000u);
        }
    }

    if (valid) {
        float* orow = tmp + (size_t)drow * HH + kg * 4;
#pragma unroll
        for (int n = 0; n < 8; ++n) {
            v4f b = *reinterpret_cast<const v4f*>(bias + n * 16 + kg * 4);
            *reinterpret_cast<v4f*>(orow + n * 16) = acc[n] + b;
        }
    }
}

// ---------------- root GEMM (fallback path only) ----------------
__global__ __launch_bounds__(256) void k_rootgemm(const unsigned short* __restrict__ hb,
                                                  const unsigned short* __restrict__ rootT,
                                                  const float* __restrict__ bias,
                                                  float* __restrict__ tmp) {
    __shared__ __align__(16) unsigned short Xs[TILE][HH + 8];
    __shared__ __align__(16) unsigned short Ws[HH][HH + 8];
    int base = blockIdx.x * TILE;
    int t = threadIdx.x;

    {
        int l = t >> 2, lr = t & 3;
        int row = base + l;
        for (int i = 0; i < 4; ++i) {
            int g = lr + 4 * i;
            uint4 v = {0u, 0u, 0u, 0u};
            if (row < NN) v = *reinterpret_cast<const uint4*>(hb + (size_t)row * HH + g * 8);
            *reinterpret_cast<uint4*>(&Xs[l][g * 8]) = v;
        }
    }
    for (int i = 0; i < 8; ++i) {
        int idx = t + 256 * i;
        int row = idx >> 4, g = idx & 15;
        *reinterpret_cast<uint4*>(&Ws[row][g * 8]) =
            *reinterpret_cast<const uint4*>(rootT + row * HH + g * 8);
    }
    __syncthreads();

    int w = t >> 6, lane = t & 63;
    int lr16 = lane & 15, kg = lane >> 4;
    v4f acc[8];
    for (int n = 0; n < 8; ++n) acc[n] = (v4f){0.f, 0.f, 0.f, 0.f};
#pragma unroll
    for (int kk = 0; kk < 4; ++kk) {
        int k0 = kk * 32 + kg * 8;
        v8bf a = *reinterpret_cast<const v8bf*>(&Xs[w * 16 + lr16][k0]);
#pragma unroll
        for (int n = 0; n < 8; ++n) {
            v8bf b = *reinterpret_cast<const v8bf*>(&Ws[n * 16 + lr16][k0]);
            acc[n] = __builtin_amdgcn_mfma_f32_16x16x32_bf16(a, b, acc[n], 0, 0, 0);
        }
    }
#pragma unroll
    for (int n = 0; n < 8; ++n)
        for (int j = 0; j < 4; ++j) {
            int row = base + w * 16 + kg * 4 + j;
            int col = n * 16 + lr16;
            if (row < NN) tmp[(size_t)row * HH + col] = acc[n][j] + bias[col];
        }
}

// ---------------- edge GEMM -> xe rows: swapped MFMA, reg accs, LDS-reuse repack --
__global__ __launch_bounds__(256) void k_edgegemm_x(const unsigned short* __restrict__ hb,
                                                    const unsigned short* __restrict__ Wt,
                                                    const int* __restrict__ src_s,
                                                    const int* __restrict__ chunk_rel,
                                                    const float* __restrict__ norm_s,
                                                    const int* __restrict__ dpos_s,
                                                    const int* __restrict__ totals,
                                                    unsigned short* __restrict__ xe) {
    int ebase = blockIdx.x * TILE;
    if (ebase >= totals[0]) return;
    __shared__ __align__(16) unsigned short S[HH * (HH + 8)];   // Ws, reused as staging
    int t = threadIdx.x;
    int rel = chunk_rel[blockIdx.x];  // single-relation chunk by construction

    const unsigned short* Wr = Wt + (size_t)rel * HH * HH;
    for (int i = 0; i < 8; ++i) {
        int idx = t + 256 * i;
        int row = idx >> 4, g = idx & 15;
        *reinterpret_cast<uint4*>(&S[row * (HH + 8) + g * 8]) =
            *reinterpret_cast<const uint4*>(Wr + row * HH + g * 8);
    }

    int w = t >> 6, lane = t & 63;
    int lr16 = lane & 15, kg = lane >> 4;
    int slot = w * 16 + lr16;
    int srow = src_s[ebase + slot];
    float nrm = norm_s[ebase + slot];

    v8bf xf[4];
    const unsigned short* hrow = hb + (size_t)srow * HH + kg * 8;
#pragma unroll
    for (int kk = 0; kk < 4; ++kk)
        xf[kk] = *reinterpret_cast<const v8bf*>(hrow + kk * 32);

    __syncthreads();   // Ws staged

    v4f acc[8];
#pragma unroll
    for (int n = 0; n < 8; ++n) acc[n] = (v4f){0.f, 0.f, 0.f, 0.f};
#pragma unroll
    for (int n = 0; n < 8; ++n)
#pragma unroll
        for (int kk = 0; kk < 4; ++kk) {
            v8bf wf = *reinterpret_cast<const v8bf*>(
                &S[(n * 16 + lr16) * (HH + 8) + kk * 32 + kg * 8]);
            acc[n] = __builtin_amdgcn_mfma_f32_16x16x32_bf16(wf, xf[kk], acc[n], 0, 0, 0);
        }

    __syncthreads();   // all Ws reads complete; reuse S[0..8192) as [64][128] staging

    int c = slot & 7;
#pragma unroll
    for (int n = 0; n < 8; ++n) {
        unsigned int w0 = pk_bf16(acc[n][0] * nrm, acc[n][1] * nrm);
        unsigned int w1 = pk_bf16(acc[n][2] * nrm, acc[n][3] * nrm);
        unsigned long long p = (unsigned long long)w0 | ((unsigned long long)w1 << 32);
        int a = n * 4 + kg;                                  // 8B granule index
        int sw = (((a >> 1) ^ c) << 1) | (a & 1);            // swizzled granule
        *reinterpret_cast<unsigned long long*>(&S[slot * HH + sw * 4]) = p;
    }
    __syncthreads();
    {
        int l = t >> 2, lr = t & 3;
        size_t drow = (size_t)dpos_s[ebase + l];
        int cs = l & 7;
        unsigned short* orow = xe + drow * HH;
#pragma unroll
        for (int i = 0; i < 4; ++i) {
            int j = lr + 4 * i;                              // 16B block 0..15
            v4u v = *reinterpret_cast<const v4u*>(&S[l * HH + (j ^ cs) * 8]);
            *reinterpret_cast<v4u*>(orow + j * 8) = v;       // cached store -> L3
        }
    }
}

// ---------------- fallback: atomic edge GEMM (if ws too small for xe) ------------
__global__ __launch_bounds__(256) void k_edgegemm_at(const unsigned short* __restrict__ hb,
                                                     const unsigned short* __restrict__ Wt,
                                                     const int* __restrict__ src_s,
                                                     const int* __restrict__ dst_s,
                                                     const int* __restrict__ chunk_rel,
                                                     const float* __restrict__ norm_s,
                                                     const int* __restrict__ totals,
                                                     float* __restrict__ tmp) {
    int ebase = blockIdx.x * TILE;
    if (ebase >= totals[0]) return;
    __shared__ __align__(16) unsigned short Xs[TILE][HH + 8];
    __shared__ __align__(16) unsigned short Ws[HH][HH + 8];
    __shared__ int   src_l[TILE];
    __shared__ int   dst_l[TILE];
    __shared__ float nrm_l[TILE];
    int t = threadIdx.x;
    if (t < TILE) {
        src_l[t] = src_s[ebase + t];
        dst_l[t] = dst_s[ebase + t];
        nrm_l[t] = norm_s[ebase + t];
    }
    int rel = chunk_rel[blockIdx.x];
    __syncthreads();
    {
        int l = t >> 2, lr = t & 3;
        int srow = src_l[l];
        for (int i = 0; i < 4; ++i) {
            int g = lr + 4 * i;
            *reinterpret_cast<uint4*>(&Xs[l][g * 8]) =
                *reinterpret_cast<const uint4*>(hb + (size_t)srow * HH + g * 8);
        }
    }
    const unsigned short* Wr = Wt + (size_t)rel * HH * HH;
    for (int i = 0; i < 8; ++i) {
        int idx = t + 256 * i;
        int row = idx >> 4, g = idx & 15;
        *reinterpret_cast<uint4*>(&Ws[row][g * 8]) =
            *reinterpret_cast<const uint4*>(Wr + row * HH + g * 8);
    }
    __syncthreads();
    int w = t >> 6, lane = t & 63;
    int lr16 = lane & 15, kg = lane >> 4;
    v4f acc[8];
    for (int n = 0; n < 8; ++n) acc[n] = (v4f){0.f, 0.f, 0.f, 0.f};
#pragma unroll
    for (int kk = 0; kk < 4; ++kk) {
        int k0 = kk * 32 + kg * 8;
        v8bf a = *reinterpret_cast<const v8bf*>(&Xs[w * 16 + lr16][k0]);
#pragma unroll
        for (int n = 0; n < 8; ++n) {
            v8bf b = *reinterpret_cast<const v8bf*>(&Ws[n * 16 + lr16][k0]);
            acc[n] = __builtin_amdgcn_mfma_f32_16x16x32_bf16(a, b, acc[n], 0, 0, 0);
        }
    }
#pragma unroll
    for (int n = 0; n < 8; ++n)
        for (int j = 0; j < 4; ++j) {
            int slot = w * 16 + kg * 4 + j;
            int col  = n * 16 + lr16;
            atomicAdd(&tmp[(size_t)dst_l[slot] * HH + col], acc[n][j] * nrm_l[slot]);
        }
}

// ---------------- BN stage 1: per-block column partial sums (no atomics) ---------
__global__ __launch_bounds__(256) void k_bnsum1(const float* __restrict__ tmp,
                                                float* __restrict__ psum,
                                                float* __restrict__ psq) {
    int t = threadIdx.x;
    int rg = t >> 5, lane = t & 31;           // 8 row-groups x 32 lanes (float4 cols)
    int base = blockIdx.x * RPB_BN;
    v4f s = {0.f, 0.f, 0.f, 0.f}, q = {0.f, 0.f, 0.f, 0.f};
#pragma unroll 4
    for (int i = 0; i < RPB_BN / 8; ++i) {
        int row = base + rg + 8 * i;
        if (row < NN) {
            v4f v = *reinterpret_cast<const v4f*>(tmp + (size_t)row * HH + lane * 4);
            s += v; q += v * v;
        }
    }
    __shared__ v4f shs[8][32], shq[8][32];
    shs[rg][lane] = s; shq[rg][lane] = q;
    __syncthreads();
    if (rg == 0) {
        v4f ts = shs[0][lane], tq = shq[0][lane];
#pragma unroll
        for (int k = 1; k < 8; ++k) { ts += shs[k][lane]; tq += shq[k][lane]; }
        int b = blockIdx.x;
#pragma unroll
        for (int j = 0; j < 4; ++j) {
            psum[(size_t)(lane * 4 + j) * NBLK_BN + b] = ts[j];
            psq [(size_t)(lane * 4 + j) * NBLK_BN + b] = tq[j];
        }
    }
}

// ---------------- BN stage 2: reduce partials, emit affine coefficients ----------
__global__ void k_bnsum2(const float* __restrict__ psum, const float* __restrict__ psq,
                         const float* __restrict__ g, const float* __restrict__ be,
                         float* __restrict__ sc_g, float* __restrict__ shf_g) {
    __shared__ float ssum[HH], ssq[HH];
    int t = threadIdx.x;
    int col = t & 127;
    const float* row = ((t < 128) ? psum : psq) + (size_t)col * NBLK_BN;
    v4f a = {0.f, 0.f, 0.f, 0.f};
    for (int i = 0; i < NBLK_BN / 4; ++i)
        a += *reinterpret_cast<const v4f*>(row + i * 4);
    float acc = a[0] + a[1] + a[2] + a[3];
    if (t < 128) ssum[col] = acc; else ssq[col] = acc;
    __syncthreads();
    if (t < 128) {
        float inv_n = 1.0f / (float)NN;
        float mean = ssum[col] * inv_n;
        float var = ssq[col] * inv_n - mean * mean;
        float sc = g[col] * rsqrtf(var + BN_EPS);
        sc_g[col] = sc;
        shf_g[col] = be[col] - mean * sc;
    }
}

// ---------------- BN apply + ReLU (vectorized float4, cvt_pk pack) ---------------
__global__ void k_bnapply(const float* __restrict__ tmp, const float* __restrict__ sc_g,
                          const float* __restrict__ shf_g,
                          unsigned short* __restrict__ hout,
                          float* __restrict__ fout, int write_bf16) {
    int idx = blockIdx.x * blockDim.x + threadIdx.x;   // float4 index
    if (idx >= NN * HH / 4) return;
    int c4 = (idx & 31) * 4;                            // HH/4 = 32 quads per row
    v4f v  = *reinterpret_cast<const v4f*>(tmp + (size_t)idx * 4);
    v4f sc = *reinterpret_cast<const v4f*>(sc_g + c4);
    v4f sh = *reinterpret_cast<const v4f*>(shf_g + c4);
    v4f r;
#pragma unroll
    for (int j = 0; j < 4; ++j) r[j] = fmaxf(v[j] * sc[j] + sh[j], 0.f);
    if (write_bf16) {
        uint2 u;
        u.x = pk_bf16(r[0], r[1]);
        u.y = pk_bf16(r[2], r[3]);
        *reinterpret_cast<uint2*>(hout + (size_t)idx * 4) = u;
    } else {
        *reinterpret_cast<v4f*>(fout + (size_t)idx * 4) = r;
    }
}

// ---------------- workspace layout (xe LAST so fallback fits small ws) -----------
constexpr size_t OFF_DEG  = 0;                                    // N*RR2*4 = 6 MB
constexpr size_t OFF_HB   = OFF_DEG + (size_t)NN * RR2 * 4;
constexpr size_t OFF_TMP  = OFF_HB + (size_t)NN * HH * 2;
constexpr size_t OFF_W1T  = OFF_TMP + (size_t)NN * HH * 4;
constexpr size_t OFF_W2T  = OFF_W1T + (size_t)RR * HH * HH * 2;
constexpr size_t OFF_R1T  = OFF_W2T + (size_t)RR * HH * HH * 2;
constexpr size_t OFF_R2T  = OFF_R1T + (size_t)HH * HH * 2;
constexpr size_t OFF_SRCS = OFF_R2T + (size_t)HH * HH * 2;
constexpr size_t OFF_DSTS = OFF_SRCS + (size_t)EPAD * 4;
constexpr size_t OFF_NRMS = OFF_DSTS + (size_t)EPAD * 4;
constexpr size_t OFF_DPOS = OFF_NRMS + (size_t)EPAD * 4;
constexpr size_t OFF_CREL = OFF_DPOS + (size_t)EPAD * 4;          // chunk -> relation
constexpr size_t OFF_CNTD = OFF_CREL + ((size_t)NCHMAX * 4 + 255 & ~(size_t)255);
constexpr size_t OFF_CNTP = OFF_CNTD + ((size_t)(NN + 1) * 4 + 255 & ~(size_t)255);
constexpr size_t OFF_OFFD = OFF_CNTP + ((size_t)(NN + 1) * 4 + 255 & ~(size_t)255);
constexpr size_t OFF_CUR2 = OFF_OFFD + ((size_t)(NN + 1) * 4 + 255 & ~(size_t)255);
constexpr size_t OFF_CURD = OFF_CUR2 + ((size_t)NN * 4 + 255 & ~(size_t)255);
constexpr size_t OFF_PERM = OFF_CURD + ((size_t)NN * 4 + 255 & ~(size_t)255);
constexpr size_t OFF_DH   = OFF_PERM + ((size_t)NN * 4 + 255 & ~(size_t)255);
constexpr size_t OFF_DC   = OFF_DH + DBKT * 4;
constexpr size_t OFF_BSUM = OFF_DC + DBKT * 4;
constexpr size_t OFF_CTRL = OFF_BSUM + ((size_t)NB_PS * 4 + 255 & ~(size_t)255);
constexpr size_t OFF_SC   = OFF_CTRL + 512;                       // 128 floats
constexpr size_t OFF_SHF  = OFF_SC + 512;
constexpr size_t OFF_PSUM = OFF_SHF + 512;                        // 128*NBLK_BN floats
constexpr size_t OFF_PSQ  = OFF_PSUM + (size_t)HH * NBLK_BN * 4;
constexpr size_t OFF_XE   = (OFF_PSQ + (size_t)HH * NBLK_BN * 4 + 255) & ~(size_t)255;
constexpr size_t WS_MIN   = OFF_XE;                               // ~102 MB (fallback)
constexpr size_t WS_FULL  = OFF_XE + (size_t)EPAD * HH * 2;       // ~256 MB

extern "C" void kernel_launch(void* const* d_in, const int* in_sizes, int n_in,
                              void* d_out, int out_size, void* d_ws, size_t ws_size,
                              hipStream_t stream) {
    const int*   x     = (const int*)d_in[0];
    const int*   eidx  = (const int*)d_in[1];   // (2,E) row-major: src then dst
    const int*   et    = (const int*)d_in[2];
    const float* emb   = (const float*)d_in[3];
    const float* W1    = (const float*)d_in[4];
    const float* root1 = (const float*)d_in[5];
    const float* b1    = (const float*)d_in[6];
    const float* g1    = (const float*)d_in[7];
    const float* be1   = (const float*)d_in[8];
    const float* W2    = (const float*)d_in[9];
    const float* root2 = (const float*)d_in[10];
    const float* b2    = (const float*)d_in[11];
    const float* g2    = (const float*)d_in[12];
    const float* be2   = (const float*)d_in[13];
    float* out = (float*)d_out;

    if (ws_size < WS_MIN) return;  // diagnosable: out stays poisoned
    const bool full = (ws_size >= WS_FULL);
    const int need_dst = full ? 0 : 1;

    char* ws = (char*)d_ws;
    unsigned int* deg16 = (unsigned int*)(ws + OFF_DEG);
    unsigned short* hb = (unsigned short*)(ws + OFF_HB);
    float* tmp    = (float*)(ws + OFF_TMP);
    unsigned short* W1t = (unsigned short*)(ws + OFF_W1T);
    unsigned short* W2t = (unsigned short*)(ws + OFF_W2T);
    unsigned short* r1t = (unsigned short*)(ws + OFF_R1T);
    unsigned short* r2t = (unsigned short*)(ws + OFF_R2T);
    int*   src_s  = (int*)(ws + OFF_SRCS);
    int*   dst_s  = (int*)(ws + OFF_DSTS);
    float* norm_s = (float*)(ws + OFF_NRMS);
    int*   dpos_s = (int*)(ws + OFF_DPOS);
    int*   crel   = (int*)(ws + OFF_CREL);
    int*   cnt_d  = (int*)(ws + OFF_CNTD);
    int*   cnt_p  = (int*)(ws + OFF_CNTP);
    int*   off2   = (int*)(ws + OFF_OFFD);
    int*   cur2   = (int*)(ws + OFF_CUR2);
    int*   cur_d  = (int*)(ws + OFF_CURD);
    int*   perm   = (int*)(ws + OFF_PERM);
    int*   dhist  = (int*)(ws + OFF_DH);
    int*   dcur   = (int*)(ws + OFF_DC);
    int*   bsum   = (int*)(ws + OFF_BSUM);
    int*   cnt    = (int*)(ws + OFF_CTRL);
    int*   cursor = cnt + 32;
    int*   totals = cnt + 64;
    float* sc_g   = (float*)(ws + OFF_SC);
    float* shf_g  = (float*)(ws + OFF_SHF);
    float* psum   = (float*)(ws + OFF_PSUM);
    float* psq    = (float*)(ws + OFF_PSQ);
    unsigned short* xe = (unsigned short*)(ws + OFF_XE);

    const int* srcp = eidx;
    const int* dstp = eidx + NE;

    hipMemsetAsync(deg16, 0, (size_t)NN * RR2 * 4, stream);
    hipMemsetAsync(cnt, 0, 512, stream);
    hipMemsetAsync(dhist, 0, DBKT * 4, stream);

    k_hist<<<(NE + 255) / 256, 256, 0, stream>>>(dstp, et, deg16, cnt);
    k_degsum<<<(NN + 255) / 256, 256, 0, stream>>>(deg16, cnt_d);
    k_scan<<<1, 256, 0, stream>>>(cnt, cursor, totals, src_s, dst_s, norm_s,
                                  dpos_s, crel, need_dst);
    k_dhist<<<(NN + 255) / 256, 256, 0, stream>>>(cnt_d, dhist);
    k_dprefix<<<1, DBKT, 0, stream>>>(dhist, dcur);
    k_dscatter<<<(NN + 255) / 256, 256, 0, stream>>>(cnt_d, dcur, perm);
    k_permcnt<<<(NN + 255) / 256, 256, 0, stream>>>(cnt_d, perm, cnt_p);
    k_psum1<<<NB_PS, 256, 0, stream>>>(cnt_p, bsum);
    k_psum2<<<1, 512, 0, stream>>>(bsum);
    k_psum3<<<NB_PS, 256, 0, stream>>>(cnt_p, bsum, off2, cur2);
    k_permcur<<<(NN + 255) / 256, 256, 0, stream>>>(off2, perm, cur_d);
    k_scatter<<<(NE + 255) / 256, 256, 0, stream>>>(srcp, dstp, et, deg16, cursor, cur_d,
                                                    src_s, dst_s, norm_s, dpos_s,
                                                    need_dst);
    k_convW<<<(RR * HH * HH + 255) / 256, 256, 0, stream>>>(W1, W1t, RR * HH * HH);
    k_convW<<<(RR * HH * HH + 255) / 256, 256, 0, stream>>>(W2, W2t, RR * HH * HH);
    k_convW<<<(HH * HH + 255) / 256, 256, 0, stream>>>(root1, r1t, HH * HH);
    k_convW<<<(HH * HH + 255) / 256, 256, 0, stream>>>(root2, r2t, HH * HH);
    k_embed<<<(NN * HH / 2 + 255) / 256, 256, 0, stream>>>(x, emb, (unsigned int*)hb);

    const unsigned short* Wts[2] = {W1t, W2t};
    const unsigned short* rts[2] = {r1t, r2t};
    const float* biases[2] = {b1, b2};
    const float* gs[2]     = {g1, g2};
    const float* bes[2]    = {be1, be2};

    for (int layer = 0; layer < 2; ++layer) {
        if (full) {
            k_edgegemm_x<<<EPAD / TILE, 256, 0, stream>>>(hb, Wts[layer], src_s, crel,
                                                          norm_s, dpos_s, totals, xe);
            k_rootagg<<<(NN + TILE - 1) / TILE, 256, 0, stream>>>(hb, rts[layer],
                                                                  biases[layer], off2,
                                                                  perm, xe, tmp);
        } else {
            k_rootgemm<<<(NN + TILE - 1) / TILE, 256, 0, stream>>>(hb, rts[layer],
                                                                   biases[layer], tmp);
            k_edgegemm_at<<<EPAD / TILE, 256, 0, stream>>>(hb, Wts[layer], src_s, dst_s,
                                                           crel, norm_s, totals, tmp);
        }
        k_bnsum1<<<NBLK_BN, 256, 0, stream>>>(tmp, psum, psq);
        k_bnsum2<<<1, 256, 0, stream>>>(psum, psq, gs[layer], bes[layer], sc_g, shf_g);
        k_bnapply<<<(NN * HH / 4 + 255) / 256, 256, 0, stream>>>(tmp, sc_g, shf_g,
                                                                 hb, out, layer == 0);
    }
}

// Round 18
// 479.314 us; speedup vs baseline: 1.0559x; 1.0556x over previous
//
#include <hip/hip_runtime.h>
#include <hip/hip_bf16.h>

// Problem constants (from reference setup_inputs)
#define NN 100000
#define HH 128
#define RR 30
#define RR2 15                      // packed 2x16-bit degree words per dst
#define NE 600000
#define TILE 64
#define EPAD (NE + RR * TILE)
#define NCHMAX (EPAD / TILE)        // max relation chunks (9405)
#define NB_PS ((NN + 255) / 256)    // 391 prefix-sum blocks
#define NBLK_BN 784                 // bn stage-1 blocks (128 rows each)
#define RPB_BN 128
#define BN_EPS 1e-5f

typedef __bf16 v8bf __attribute__((ext_vector_type(8)));
typedef float  v4f  __attribute__((ext_vector_type(4)));
typedef unsigned int v4u __attribute__((ext_vector_type(4)));

static __device__ __forceinline__ unsigned short f2b(float f) {
    unsigned int u = __float_as_uint(f);
    unsigned int r = (u + 0x7FFF + ((u >> 16) & 1)) >> 16;  // RNE
    return (unsigned short)r;
}

// HW packed f32->bf16 (RNE), gfx950
static __device__ __forceinline__ unsigned int pk_bf16(float lo, float hi) {
    unsigned int r;
    asm("v_cvt_pk_bf16_f32 %0, %1, %2" : "=v"(r) : "v"(lo), "v"(hi));
    return r;
}

// ---------------- histogram: packed per-(dst,rel) degree + per-rel count --------
__global__ void k_hist(const int* __restrict__ dst, const int* __restrict__ et,
                       unsigned int* __restrict__ deg16, int* __restrict__ cnt) {
    __shared__ int lh[RR];
    int t = threadIdx.x;
    if (t < RR) lh[t] = 0;
    __syncthreads();
    int i = blockIdx.x * blockDim.x + t;
    if (i < NE) {
        int d = dst[i], r = et[i];
        atomicAdd(&deg16[(size_t)d * RR2 + (r >> 1)], 1u << ((r & 1) * 16));
        atomicAdd(&lh[r], 1);             // LDS
    }
    __syncthreads();
    if (t < RR && lh[t]) atomicAdd(&cnt[t], lh[t]);
}

// ---------------- per-dst degree from deg16 (coalesced) ----------------
__global__ void k_degsum(const unsigned int* __restrict__ deg16,
                         int* __restrict__ cnt_d) {
    int d = blockIdx.x * blockDim.x + threadIdx.x;
    if (d >= NN) return;
    int s = 0;
#pragma unroll
    for (int r2 = 0; r2 < RR2; ++r2) {
        unsigned int v = deg16[(size_t)d * RR2 + r2];
        s += (int)(v & 0xffffu) + (int)(v >> 16);
    }
    cnt_d[d] = s;
}

// ---------------- scan: relation chunk offsets, pad fill, chunk_rel, cursors ------
__global__ void k_scan(const int* __restrict__ cnt, int* __restrict__ cursor,
                       int* __restrict__ totals,
                       int* __restrict__ src_s, int* __restrict__ dst_s,
                       float* __restrict__ norm_s, int* __restrict__ dpos_s,
                       int* __restrict__ chunk_rel, int need_dst) {
    __shared__ int off[RR + 1];
    if (threadIdx.x == 0) {
        int acc = 0;
        for (int r = 0; r < RR; ++r) {
            off[r] = acc;
            acc += (cnt[r] + TILE - 1) / TILE;
        }
        off[RR] = acc;
        totals[0] = acc * TILE;
    }
    __syncthreads();
    for (int r = 0; r < RR; ++r) {
        for (int c = off[r] + (int)threadIdx.x; c < off[r + 1]; c += blockDim.x)
            chunk_rel[c] = r;
        int begin = off[r] * TILE + cnt[r];
        int end   = off[r + 1] * TILE;
        for (int p = begin + (int)threadIdx.x; p < end; p += blockDim.x) {
            src_s[p] = 0; norm_s[p] = 0.f;
            dpos_s[p] = NE;  // pads dump zeros into unread row NE of xe
            if (need_dst) dst_s[p] = 0;
        }
    }
    if (threadIdx.x == 0)
        for (int r = 0; r < RR; ++r) cursor[r] = off[r] * TILE;
}

// ---------------- hierarchical prefix sum over cnt_d (100k bins) ----------------
__global__ void k_psum1(const int* __restrict__ c, int* __restrict__ bsum) {
    __shared__ int sh[256];
    int i = blockIdx.x * 256 + threadIdx.x;
    sh[threadIdx.x] = (i < NN) ? c[i] : 0;
    __syncthreads();
    for (int s = 128; s > 0; s >>= 1) {
        if (threadIdx.x < s) sh[threadIdx.x] += sh[threadIdx.x + s];
        __syncthreads();
    }
    if (threadIdx.x == 0) bsum[blockIdx.x] = sh[0];
}

__global__ void k_psum2(int* __restrict__ bsum) {
    __shared__ int sh[512];
    int t = threadIdx.x;
    sh[t] = (t < NB_PS) ? bsum[t] : 0;
    __syncthreads();
    if (t == 0) {
        int acc = 0;
        for (int b = 0; b < NB_PS; ++b) { int v = sh[b]; sh[b] = acc; acc += v; }
    }
    __syncthreads();
    if (t < NB_PS) bsum[t] = sh[t];
}

__global__ void k_psum3(const int* __restrict__ c, const int* __restrict__ bscan,
                        int* __restrict__ off, int* __restrict__ cur) {
    __shared__ int sh[256];
    int t = threadIdx.x;
    int i = blockIdx.x * 256 + t;
    int v = (i < NN) ? c[i] : 0;
    sh[t] = v;
    __syncthreads();
    for (int s = 1; s < 256; s <<= 1) {   // Hillis-Steele inclusive scan
        int a = (t >= s) ? sh[t - s] : 0;
        __syncthreads();
        sh[t] += a;
        __syncthreads();
    }
    int excl = sh[t] - v + bscan[blockIdx.x];
    if (i < NN) { off[i] = excl; cur[i] = excl; }
    if (i == 0) off[NN] = NE;
}

// ---------------- scatter into relation-sorted arrays + dst-slot assignment -------
__global__ void k_scatter(const int* __restrict__ src, const int* __restrict__ dst,
                          const int* __restrict__ et,
                          const unsigned int* __restrict__ deg16,
                          int* __restrict__ cursor, int* __restrict__ cursor_dst,
                          int* __restrict__ src_s, int* __restrict__ dst_s,
                          float* __restrict__ norm_s, int* __restrict__ dpos_s,
                          int need_dst) {
    __shared__ int lh[RR];
    __shared__ int lbase[RR];
    int t = threadIdx.x;
    if (t < RR) lh[t] = 0;
    __syncthreads();
    int i = blockIdx.x * blockDim.x + t;
    int r = 0, d = 0, lrank = 0;
    bool valid = (i < NE);
    if (valid) {
        r = et[i]; d = dst[i];
        lrank = atomicAdd(&lh[r], 1);
    }
    __syncthreads();
    if (t < RR && lh[t]) lbase[t] = atomicAdd(&cursor[t], lh[t]);
    __syncthreads();
    if (valid) {
        int pos = lbase[r] + lrank;
        src_s[pos] = src[i];
        if (need_dst) dst_s[pos] = d;
        int dg = (int)((deg16[(size_t)d * RR2 + (r >> 1)] >> ((r & 1) * 16)) & 0xffffu);
        norm_s[pos] = 1.0f / (float)(dg > 1 ? dg : 1);
        dpos_s[pos] = atomicAdd(&cursor_dst[d], 1);  // slot in dst-sorted xe
    }
}

// ---------------- convert+transpose weights to bf16: Wt[m][c][k] = W[m][k][c] ----
__global__ void k_convW(const float* __restrict__ W, unsigned short* __restrict__ Wt,
                        int total) {
    int idx = blockIdx.x * blockDim.x + threadIdx.x;
    if (idx >= total) return;
    int m = idx / (HH * HH);
    int rem = idx % (HH * HH);
    int k = rem / HH, c = rem % HH;
    Wt[m * HH * HH + c * HH + k] = f2b(W[idx]);
}

// ---------------- embedding lookup -> bf16 h (2 elems/thread, cvt_pk) ------------
__global__ void k_embed(const int* __restrict__ x, const float* __restrict__ emb,
                        unsigned int* __restrict__ hb2) {
    int idx = blockIdx.x * blockDim.x + threadIdx.x;   // uint index (2 bf16)
    if (idx >= NN * HH / 2) return;
    int i = idx >> 6;                 // HH/2 = 64 pairs per row
    int j2 = (idx & 63) * 2;
    const float* p = emb + (size_t)x[i] * HH + j2;
    hb2[idx] = pk_bf16(p[0], p[1]);
}

// ---------------- fused root GEMM + edge aggregation (full path) ----------------
// Split-Ws staging (17.4KB LDS) + 2-row-unrolled edge walk for MLP.
__global__ __launch_bounds__(256) void k_rootagg(const unsigned short* __restrict__ hb,
                                                 const unsigned short* __restrict__ rootT,
                                                 const float* __restrict__ bias,
                                                 const int* __restrict__ off,
                                                 const unsigned short* __restrict__ xe,
                                                 float* __restrict__ tmp) {
    __shared__ __align__(16) unsigned short Ws[64][HH + 8];   // half of root
    int t = threadIdx.x;
    int base = blockIdx.x * TILE;

    int w = t >> 6, lane = t & 63;
    int lr16 = lane & 15, kg = lane >> 4;
    int slot = w * 16 + lr16;
    int drow = base + slot;
    bool valid = (drow < NN);
    int dsafe = valid ? drow : 0;

    v8bf xf[4];
    const unsigned short* hrow = hb + (size_t)dsafe * HH + kg * 8;
#pragma unroll
    for (int kk = 0; kk < 4; ++kk)
        xf[kk] = *reinterpret_cast<const v8bf*>(hrow + kk * 32);

    v4f acc[8];
#pragma unroll
    for (int n = 0; n < 8; ++n) acc[n] = (v4f){0.f, 0.f, 0.f, 0.f};

    // phase A: root rows 0..63 -> n = 0..3
    for (int i = 0; i < 4; ++i) {
        int idx = t + 256 * i;                       // 1024 uint4 chunks
        int row = idx >> 4, g = idx & 15;
        *reinterpret_cast<uint4*>(&Ws[row][g * 8]) =
            *reinterpret_cast<const uint4*>(rootT + row * HH + g * 8);
    }
    __syncthreads();
#pragma unroll
    for (int n = 0; n < 4; ++n)
#pragma unroll
        for (int kk = 0; kk < 4; ++kk) {
            v8bf wf = *reinterpret_cast<const v8bf*>(&Ws[n * 16 + lr16][kk * 32 + kg * 8]);
            acc[n] = __builtin_amdgcn_mfma_f32_16x16x32_bf16(wf, xf[kk], acc[n], 0, 0, 0);
        }
    __syncthreads();
    // phase B: root rows 64..127 -> n = 4..7
    for (int i = 0; i < 4; ++i) {
        int idx = t + 256 * i;
        int row = idx >> 4, g = idx & 15;
        *reinterpret_cast<uint4*>(&Ws[row][g * 8]) =
            *reinterpret_cast<const uint4*>(rootT + (64 + row) * HH + g * 8);
    }
    __syncthreads();
#pragma unroll
    for (int n = 4; n < 8; ++n)
#pragma unroll
        for (int kk = 0; kk < 4; ++kk) {
            v8bf wf = *reinterpret_cast<const v8bf*>(&Ws[(n - 4) * 16 + lr16][kk * 32 + kg * 8]);
            acc[n] = __builtin_amdgcn_mfma_f32_16x16x32_bf16(wf, xf[kk], acc[n], 0, 0, 0);
        }

    // edge-sum walk: contiguous span, 2-row unroll (16 loads in flight)
    int s = valid ? off[drow] : 0;
    int e = valid ? off[drow + 1] : 0;
    int p = s;
    for (; p + 1 < e; p += 2) {
        const unsigned short* xr0 = xe + (size_t)p * HH + kg * 4;
        const unsigned short* xr1 = xr0 + HH;
        uint2 u0[8], u1[8];
#pragma unroll
        for (int n = 0; n < 8; ++n) {
            u0[n] = *reinterpret_cast<const uint2*>(xr0 + n * 16);
            u1[n] = *reinterpret_cast<const uint2*>(xr1 + n * 16);
        }
#pragma unroll
        for (int n = 0; n < 8; ++n) {
            acc[n][0] += __uint_as_float(u0[n].x << 16) + __uint_as_float(u1[n].x << 16);
            acc[n][1] += __uint_as_float(u0[n].x & 0xffff0000u) + __uint_as_float(u1[n].x & 0xffff0000u);
            acc[n][2] += __uint_as_float(u0[n].y << 16) + __uint_as_float(u1[n].y << 16);
            acc[n][3] += __uint_as_float(u0[n].y & 0xffff0000u) + __uint_as_float(u1[n].y & 0xffff0000u);
        }
    }
    if (p < e) {
        const unsigned short* xr = xe + (size_t)p * HH + kg * 4;
#pragma unroll
        for (int n = 0; n < 8; ++n) {
            uint2 u = *reinterpret_cast<const uint2*>(xr + n * 16);
            acc[n][0] += __uint_as_float(u.x << 16);
            acc[n][1] += __uint_as_float(u.x & 0xffff0000u);
            acc[n][2] += __uint_as_float(u.y << 16);
            acc[n][3] += __uint_as_float(u.y & 0xffff0000u);
        }
    }

    if (valid) {
        float* orow = tmp + (size_t)drow * HH + kg * 4;
#pragma unroll
        for (int n = 0; n < 8; ++n) {
            v4f b = *reinterpret_cast<const v4f*>(bias + n * 16 + kg * 4);
            *reinterpret_cast<v4f*>(orow + n * 16) = acc[n] + b;
        }
    }
}

// ---------------- root GEMM (fallback path only) ----------------
__global__ __launch_bounds__(256) void k_rootgemm(const unsigned short* __restrict__ hb,
                                                  const unsigned short* __restrict__ rootT,
                                                  const float* __restrict__ bias,
                                                  float* __restrict__ tmp) {
    __shared__ __align__(16) unsigned short Xs[TILE][HH + 8];
    __shared__ __align__(16) unsigned short Ws[HH][HH + 8];
    int base = blockIdx.x * TILE;
    int t = threadIdx.x;

    {
        int l = t >> 2, lr = t & 3;
        int row = base + l;
        for (int i = 0; i < 4; ++i) {
            int g = lr + 4 * i;
            uint4 v = {0u, 0u, 0u, 0u};
            if (row < NN) v = *reinterpret_cast<const uint4*>(hb + (size_t)row * HH + g * 8);
            *reinterpret_cast<uint4*>(&Xs[l][g * 8]) = v;
        }
    }
    for (int i = 0; i < 8; ++i) {
        int idx = t + 256 * i;
        int row = idx >> 4, g = idx & 15;
        *reinterpret_cast<uint4*>(&Ws[row][g * 8]) =
            *reinterpret_cast<const uint4*>(rootT + row * HH + g * 8);
    }
    __syncthreads();

    int w = t >> 6, lane = t & 63;
    int lr16 = lane & 15, kg = lane >> 4;
    v4f acc[8];
    for (int n = 0; n < 8; ++n) acc[n] = (v4f){0.f, 0.f, 0.f, 0.f};
#pragma unroll
    for (int kk = 0; kk < 4; ++kk) {
        int k0 = kk * 32 + kg * 8;
        v8bf a = *reinterpret_cast<const v8bf*>(&Xs[w * 16 + lr16][k0]);
#pragma unroll
        for (int n = 0; n < 8; ++n) {
            v8bf b = *reinterpret_cast<const v8bf*>(&Ws[n * 16 + lr16][k0]);
            acc[n] = __builtin_amdgcn_mfma_f32_16x16x32_bf16(a, b, acc[n], 0, 0, 0);
        }
    }
#pragma unroll
    for (int n = 0; n < 8; ++n)
        for (int j = 0; j < 4; ++j) {
            int row = base + w * 16 + kg * 4 + j;
            int col = n * 16 + lr16;
            if (row < NN) tmp[(size_t)row * HH + col] = acc[n][j] + bias[col];
        }
}

// ---------------- edge GEMM -> xe rows: swapped MFMA, reg accs, LDS-reuse repack --
__global__ __launch_bounds__(256) void k_edgegemm_x(const unsigned short* __restrict__ hb,
                                                    const unsigned short* __restrict__ Wt,
                                                    const int* __restrict__ src_s,
                                                    const int* __restrict__ chunk_rel,
                                                    const float* __restrict__ norm_s,
                                                    const int* __restrict__ dpos_s,
                                                    const int* __restrict__ totals,
                                                    unsigned short* __restrict__ xe) {
    int ebase = blockIdx.x * TILE;
    if (ebase >= totals[0]) return;
    __shared__ __align__(16) unsigned short S[HH * (HH + 8)];   // Ws, reused as staging
    int t = threadIdx.x;
    int rel = chunk_rel[blockIdx.x];  // single-relation chunk by construction

    const unsigned short* Wr = Wt + (size_t)rel * HH * HH;
    for (int i = 0; i < 8; ++i) {
        int idx = t + 256 * i;
        int row = idx >> 4, g = idx & 15;
        *reinterpret_cast<uint4*>(&S[row * (HH + 8) + g * 8]) =
            *reinterpret_cast<const uint4*>(Wr + row * HH + g * 8);
    }

    int w = t >> 6, lane = t & 63;
    int lr16 = lane & 15, kg = lane >> 4;
    int slot = w * 16 + lr16;
    int srow = src_s[ebase + slot];
    float nrm = norm_s[ebase + slot];

    v8bf xf[4];
    const unsigned short* hrow = hb + (size_t)srow * HH + kg * 8;
#pragma unroll
    for (int kk = 0; kk < 4; ++kk)
        xf[kk] = *reinterpret_cast<const v8bf*>(hrow + kk * 32);

    __syncthreads();   // Ws staged

    v4f acc[8];
#pragma unroll
    for (int n = 0; n < 8; ++n) acc[n] = (v4f){0.f, 0.f, 0.f, 0.f};
#pragma unroll
    for (int n = 0; n < 8; ++n)
#pragma unroll
        for (int kk = 0; kk < 4; ++kk) {
            v8bf wf = *reinterpret_cast<const v8bf*>(
                &S[(n * 16 + lr16) * (HH + 8) + kk * 32 + kg * 8]);
            acc[n] = __builtin_amdgcn_mfma_f32_16x16x32_bf16(wf, xf[kk], acc[n], 0, 0, 0);
        }

    __syncthreads();   // all Ws reads complete; reuse S[0..8192) as [64][128] staging

    int c = slot & 7;
#pragma unroll
    for (int n = 0; n < 8; ++n) {
        unsigned int w0 = pk_bf16(acc[n][0] * nrm, acc[n][1] * nrm);
        unsigned int w1 = pk_bf16(acc[n][2] * nrm, acc[n][3] * nrm);
        unsigned long long p = (unsigned long long)w0 | ((unsigned long long)w1 << 32);
        int a = n * 4 + kg;                                  // 8B granule index
        int sw = (((a >> 1) ^ c) << 1) | (a & 1);            // swizzled granule
        *reinterpret_cast<unsigned long long*>(&S[slot * HH + sw * 4]) = p;
    }
    __syncthreads();
    {
        int l = t >> 2, lr = t & 3;
        size_t drow = (size_t)dpos_s[ebase + l];
        int cs = l & 7;
        unsigned short* orow = xe + drow * HH;
#pragma unroll
        for (int i = 0; i < 4; ++i) {
            int j = lr + 4 * i;                              // 16B block 0..15
            v4u v = *reinterpret_cast<const v4u*>(&S[l * HH + (j ^ cs) * 8]);
            *reinterpret_cast<v4u*>(orow + j * 8) = v;       // cached store -> L3
        }
    }
}

// ---------------- fallback: atomic edge GEMM (if ws too small for xe) ------------
__global__ __launch_bounds__(256) void k_edgegemm_at(const unsigned short* __restrict__ hb,
                                                     const unsigned short* __restrict__ Wt,
                                                     const int* __restrict__ src_s,
                                                     const int* __restrict__ dst_s,
                                                     const int* __restrict__ chunk_rel,
                                                     const float* __restrict__ norm_s,
                                                     const int* __restrict__ totals,
                                                     float* __restrict__ tmp) {
    int ebase = blockIdx.x * TILE;
    if (ebase >= totals[0]) return;
    __shared__ __align__(16) unsigned short Xs[TILE][HH + 8];
    __shared__ __align__(16) unsigned short Ws[HH][HH + 8];
    __shared__ int   src_l[TILE];
    __shared__ int   dst_l[TILE];
    __shared__ float nrm_l[TILE];
    int t = threadIdx.x;
    if (t < TILE) {
        src_l[t] = src_s[ebase + t];
        dst_l[t] = dst_s[ebase + t];
        nrm_l[t] = norm_s[ebase + t];
    }
    int rel = chunk_rel[blockIdx.x];
    __syncthreads();
    {
        int l = t >> 2, lr = t & 3;
        int srow = src_l[l];
        for (int i = 0; i < 4; ++i) {
            int g = lr + 4 * i;
            *reinterpret_cast<uint4*>(&Xs[l][g * 8]) =
                *reinterpret_cast<const uint4*>(hb + (size_t)srow * HH + g * 8);
        }
    }
    const unsigned short* Wr = Wt + (size_t)rel * HH * HH;
    for (int i = 0; i < 8; ++i) {
        int idx = t + 256 * i;
        int row = idx >> 4, g = idx & 15;
        *reinterpret_cast<uint4*>(&Ws[row][g * 8]) =
            *reinterpret_cast<const uint4*>(Wr + row * HH + g * 8);
    }
    __syncthreads();
    int w = t >> 6, lane = t & 63;
    int lr16 = lane & 15, kg = lane >> 4;
    v4f acc[8];
    for (int n = 0; n < 8; ++n) acc[n] = (v4f){0.f, 0.f, 0.f, 0.f};
#pragma unroll
    for (int kk = 0; kk < 4; ++kk) {
        int k0 = kk * 32 + kg * 8;
        v8bf a = *reinterpret_cast<const v8bf*>(&Xs[w * 16 + lr16][k0]);
#pragma unroll
        for (int n = 0; n < 8; ++n) {
            v8bf b = *reinterpret_cast<const v8bf*>(&Ws[n * 16 + lr16][k0]);
            acc[n] = __builtin_amdgcn_mfma_f32_16x16x32_bf16(a, b, acc[n], 0, 0, 0);
        }
    }
#pragma unroll
    for (int n = 0; n < 8; ++n)
        for (int j = 0; j < 4; ++j) {
            int slot = w * 16 + kg * 4 + j;
            int col  = n * 16 + lr16;
            atomicAdd(&tmp[(size_t)dst_l[slot] * HH + col], acc[n][j] * nrm_l[slot]);
        }
}

// ---------------- BN stage 1: per-block column partial sums (no atomics) ---------
__global__ __launch_bounds__(256) void k_bnsum1(const float* __restrict__ tmp,
                                                float* __restrict__ psum,
                                                float* __restrict__ psq) {
    int t = threadIdx.x;
    int rg = t >> 5, lane = t & 31;           // 8 row-groups x 32 lanes (float4 cols)
    int base = blockIdx.x * RPB_BN;
    v4f s = {0.f, 0.f, 0.f, 0.f}, q = {0.f, 0.f, 0.f, 0.f};
#pragma unroll 4
    for (int i = 0; i < RPB_BN / 8; ++i) {
        int row = base + rg + 8 * i;
        if (row < NN) {
            v4f v = *reinterpret_cast<const v4f*>(tmp + (size_t)row * HH + lane * 4);
            s += v; q += v * v;
        }
    }
    __shared__ v4f shs[8][32], shq[8][32];
    shs[rg][lane] = s; shq[rg][lane] = q;
    __syncthreads();
    if (rg == 0) {
        v4f ts = shs[0][lane], tq = shq[0][lane];
#pragma unroll
        for (int k = 1; k < 8; ++k) { ts += shs[k][lane]; tq += shq[k][lane]; }
        int b = blockIdx.x;
#pragma unroll
        for (int j = 0; j < 4; ++j) {
            psum[(size_t)(lane * 4 + j) * NBLK_BN + b] = ts[j];
            psq [(size_t)(lane * 4 + j) * NBLK_BN + b] = tq[j];
        }
    }
}

// ---------------- BN stage 2: reduce partials, emit affine coefficients ----------
__global__ void k_bnsum2(const float* __restrict__ psum, const float* __restrict__ psq,
                         const float* __restrict__ g, const float* __restrict__ be,
                         float* __restrict__ sc_g, float* __restrict__ shf_g) {
    __shared__ float ssum[HH], ssq[HH];
    int t = threadIdx.x;
    int col = t & 127;
    const float* row = ((t < 128) ? psum : psq) + (size_t)col * NBLK_BN;
    v4f a = {0.f, 0.f, 0.f, 0.f};
    for (int i = 0; i < NBLK_BN / 4; ++i)
        a += *reinterpret_cast<const v4f*>(row + i * 4);
    float acc = a[0] + a[1] + a[2] + a[3];
    if (t < 128) ssum[col] = acc; else ssq[col] = acc;
    __syncthreads();
    if (t < 128) {
        float inv_n = 1.0f / (float)NN;
        float mean = ssum[col] * inv_n;
        float var = ssq[col] * inv_n - mean * mean;
        float sc = g[col] * rsqrtf(var + BN_EPS);
        sc_g[col] = sc;
        shf_g[col] = be[col] - mean * sc;
    }
}

// ---------------- BN apply + ReLU (vectorized float4, cvt_pk pack) ---------------
__global__ void k_bnapply(const float* __restrict__ tmp, const float* __restrict__ sc_g,
                          const float* __restrict__ shf_g,
                          unsigned short* __restrict__ hout,
                          float* __restrict__ fout, int write_bf16) {
    int idx = blockIdx.x * blockDim.x + threadIdx.x;   // float4 index
    if (idx >= NN * HH / 4) return;
    int c4 = (idx & 31) * 4;                            // HH/4 = 32 quads per row
    v4f v  = *reinterpret_cast<const v4f*>(tmp + (size_t)idx * 4);
    v4f sc = *reinterpret_cast<const v4f*>(sc_g + c4);
    v4f sh = *reinterpret_cast<const v4f*>(shf_g + c4);
    v4f r;
#pragma unroll
    for (int j = 0; j < 4; ++j) r[j] = fmaxf(v[j] * sc[j] + sh[j], 0.f);
    if (write_bf16) {
        uint2 u;
        u.x = pk_bf16(r[0], r[1]);
        u.y = pk_bf16(r[2], r[3]);
        *reinterpret_cast<uint2*>(hout + (size_t)idx * 4) = u;
    } else {
        *reinterpret_cast<v4f*>(fout + (size_t)idx * 4) = r;
    }
}

// ---------------- workspace layout (xe LAST so fallback fits small ws) -----------
constexpr size_t OFF_DEG  = 0;                                    // N*RR2*4 = 6 MB
constexpr size_t OFF_HB   = OFF_DEG + (size_t)NN * RR2 * 4;
constexpr size_t OFF_TMP  = OFF_HB + (size_t)NN * HH * 2;
constexpr size_t OFF_W1T  = OFF_TMP + (size_t)NN * HH * 4;
constexpr size_t OFF_W2T  = OFF_W1T + (size_t)RR * HH * HH * 2;
constexpr size_t OFF_R1T  = OFF_W2T + (size_t)RR * HH * HH * 2;
constexpr size_t OFF_R2T  = OFF_R1T + (size_t)HH * HH * 2;
constexpr size_t OFF_SRCS = OFF_R2T + (size_t)HH * HH * 2;
constexpr size_t OFF_DSTS = OFF_SRCS + (size_t)EPAD * 4;
constexpr size_t OFF_NRMS = OFF_DSTS + (size_t)EPAD * 4;
constexpr size_t OFF_DPOS = OFF_NRMS + (size_t)EPAD * 4;
constexpr size_t OFF_CREL = OFF_DPOS + (size_t)EPAD * 4;          // chunk -> relation
constexpr size_t OFF_CNTD = OFF_CREL + ((size_t)NCHMAX * 4 + 255 & ~(size_t)255);
constexpr size_t OFF_OFFD = OFF_CNTD + ((size_t)(NN + 1) * 4 + 255 & ~(size_t)255);
constexpr size_t OFF_CURD = OFF_OFFD + ((size_t)(NN + 1) * 4 + 255 & ~(size_t)255);
constexpr size_t OFF_BSUM = OFF_CURD + ((size_t)NN * 4 + 255 & ~(size_t)255);
constexpr size_t OFF_CTRL = OFF_BSUM + ((size_t)NB_PS * 4 + 255 & ~(size_t)255);
constexpr size_t OFF_SC   = OFF_CTRL + 512;                       // 128 floats
constexpr size_t OFF_SHF  = OFF_SC + 512;
constexpr size_t OFF_PSUM = OFF_SHF + 512;                        // 128*NBLK_BN floats
constexpr size_t OFF_PSQ  = OFF_PSUM + (size_t)HH * NBLK_BN * 4;
constexpr size_t OFF_XE   = (OFF_PSQ + (size_t)HH * NBLK_BN * 4 + 255) & ~(size_t)255;
constexpr size_t WS_MIN   = OFF_XE;                               // ~100 MB (fallback)
constexpr size_t WS_FULL  = OFF_XE + (size_t)EPAD * HH * 2;       // ~254 MB

extern "C" void kernel_launch(void* const* d_in, const int* in_sizes, int n_in,
                              void* d_out, int out_size, void* d_ws, size_t ws_size,
                              hipStream_t stream) {
    const int*   x     = (const int*)d_in[0];
    const int*   eidx  = (const int*)d_in[1];   // (2,E) row-major: src then dst
    const int*   et    = (const int*)d_in[2];
    const float* emb   = (const float*)d_in[3];
    const float* W1    = (const float*)d_in[4];
    const float* root1 = (const float*)d_in[5];
    const float* b1    = (const float*)d_in[6];
    const float* g1    = (const float*)d_in[7];
    const float* be1   = (const float*)d_in[8];
    const float* W2    = (const float*)d_in[9];
    const float* root2 = (const float*)d_in[10];
    const float* b2    = (const float*)d_in[11];
    const float* g2    = (const float*)d_in[12];
    const float* be2   = (const float*)d_in[13];
    float* out = (float*)d_out;

    if (ws_size < WS_MIN) return;  // diagnosable: out stays poisoned
    const bool full = (ws_size >= WS_FULL);
    const int need_dst = full ? 0 : 1;

    char* ws = (char*)d_ws;
    unsigned int* deg16 = (unsigned int*)(ws + OFF_DEG);
    unsigned short* hb = (unsigned short*)(ws + OFF_HB);
    float* tmp    = (float*)(ws + OFF_TMP);
    unsigned short* W1t = (unsigned short*)(ws + OFF_W1T);
    unsigned short* W2t = (unsigned short*)(ws + OFF_W2T);
    unsigned short* r1t = (unsigned short*)(ws + OFF_R1T);
    unsigned short* r2t = (unsigned short*)(ws + OFF_R2T);
    int*   src_s  = (int*)(ws + OFF_SRCS);
    int*   dst_s  = (int*)(ws + OFF_DSTS);
    float* norm_s = (float*)(ws + OFF_NRMS);
    int*   dpos_s = (int*)(ws + OFF_DPOS);
    int*   crel   = (int*)(ws + OFF_CREL);
    int*   cnt_d  = (int*)(ws + OFF_CNTD);
    int*   off_d  = (int*)(ws + OFF_OFFD);
    int*   cur_d  = (int*)(ws + OFF_CURD);
    int*   bsum   = (int*)(ws + OFF_BSUM);
    int*   cnt    = (int*)(ws + OFF_CTRL);
    int*   cursor = cnt + 32;
    int*   totals = cnt + 64;
    float* sc_g   = (float*)(ws + OFF_SC);
    float* shf_g  = (float*)(ws + OFF_SHF);
    float* psum   = (float*)(ws + OFF_PSUM);
    float* psq    = (float*)(ws + OFF_PSQ);
    unsigned short* xe = (unsigned short*)(ws + OFF_XE);

    const int* srcp = eidx;
    const int* dstp = eidx + NE;

    hipMemsetAsync(deg16, 0, (size_t)NN * RR2 * 4, stream);
    hipMemsetAsync(cnt, 0, 512, stream);

    k_hist<<<(NE + 255) / 256, 256, 0, stream>>>(dstp, et, deg16, cnt);
    k_degsum<<<(NN + 255) / 256, 256, 0, stream>>>(deg16, cnt_d);
    k_scan<<<1, 256, 0, stream>>>(cnt, cursor, totals, src_s, dst_s, norm_s,
                                  dpos_s, crel, need_dst);
    k_psum1<<<NB_PS, 256, 0, stream>>>(cnt_d, bsum);
    k_psum2<<<1, 512, 0, stream>>>(bsum);
    k_psum3<<<NB_PS, 256, 0, stream>>>(cnt_d, bsum, off_d, cur_d);
    k_scatter<<<(NE + 255) / 256, 256, 0, stream>>>(srcp, dstp, et, deg16, cursor, cur_d,
                                                    src_s, dst_s, norm_s, dpos_s,
                                                    need_dst);
    k_convW<<<(RR * HH * HH + 255) / 256, 256, 0, stream>>>(W1, W1t, RR * HH * HH);
    k_convW<<<(RR * HH * HH + 255) / 256, 256, 0, stream>>>(W2, W2t, RR * HH * HH);
    k_convW<<<(HH * HH + 255) / 256, 256, 0, stream>>>(root1, r1t, HH * HH);
    k_convW<<<(HH * HH + 255) / 256, 256, 0, stream>>>(root2, r2t, HH * HH);
    k_embed<<<(NN * HH / 2 + 255) / 256, 256, 0, stream>>>(x, emb, (unsigned int*)hb);

    const unsigned short* Wts[2] = {W1t, W2t};
    const unsigned short* rts[2] = {r1t, r2t};
    const float* biases[2] = {b1, b2};
    const float* gs[2]     = {g1, g2};
    const float* bes[2]    = {be1, be2};

    for (int layer = 0; layer < 2; ++layer) {
        if (full) {
            k_edgegemm_x<<<EPAD / TILE, 256, 0, stream>>>(hb, Wts[layer], src_s, crel,
                                                          norm_s, dpos_s, totals, xe);
            k_rootagg<<<(NN + TILE - 1) / TILE, 256, 0, stream>>>(hb, rts[layer],
                                                                  biases[layer], off_d,
                                                                  xe, tmp);
        } else {
            k_rootgemm<<<(NN + TILE - 1) / TILE, 256, 0, stream>>>(hb, rts[layer],
                                                                   biases[layer], tmp);
            k_edgegemm_at<<<EPAD / TILE, 256, 0, stream>>>(hb, Wts[layer], src_s, dst_s,
                                                           crel, norm_s, totals, tmp);
        }
        k_bnsum1<<<NBLK_BN, 256, 0, stream>>>(tmp, psum, psq);
        k_bnsum2<<<1, 256, 0, stream>>>(psum, psq, gs[layer], bes[layer], sc_g, shf_g);
        k_bnapply<<<(NN * HH / 4 + 255) / 256, 256, 0, stream>>>(tmp, sc_g, shf_g,
                                                                 hb, out, layer == 0);
    }
}